// Round 1
// baseline (917.984 us; speedup 1.0000x reference)
//
#include <hip/hip_runtime.h>
#include <hip/hip_bf16.h>
#include <stdint.h>

// MPNN latency predictor, MI355X.
// Structure: ew=(E,64,64) edge weights materialized ONCE in bf16 (256MB, loop-
// invariant); msg kernel streams it 3x (HBM-bound); all GEMM-shaped work via
// mfma_f32_16x16x32_bf16 (fp32 accum); gates/decoder fp32 for precision.

#define N_NODES 32768
#define N_EDGES 32768
#define STEPS 3

typedef __attribute__((ext_vector_type(8))) short short8;   // 8 bf16 = 4 VGPRs
typedef __attribute__((ext_vector_type(4))) float float4v;  // MFMA C/D

__device__ __forceinline__ float bf2f(unsigned short u) {
    union { unsigned int i; float f; } v; v.i = ((unsigned int)u) << 16; return v.f;
}
__device__ __forceinline__ unsigned short f2bf(float f) {  // RNE
    union { float f; unsigned int i; } v; v.f = f;
    unsigned int x = v.i;
    return (unsigned short)((x + 0x7fffu + ((x >> 16) & 1u)) >> 16);
}

// ---- one-time weight prep: bf16 copies (+ transpose of root) ----
__global__ __launch_bounds__(256) void k_prep(
    const float* __restrict__ We2, const float* __restrict__ root,
    const float* __restrict__ Whh, const float* __restrict__ Wih,
    unsigned short* __restrict__ we2b, unsigned short* __restrict__ b1b,
    unsigned short* __restrict__ wihb)
{
    int i = blockIdx.x * 256 + threadIdx.x;
    if (i < 262144) {
        we2b[i] = f2bf(We2[i]);
    } else if (i < 262144 + 16384) {
        int j = i - 262144; int c = j >> 6, k = j & 63;
        float v = (c < 64) ? root[k * 64 + c]            // rootT: B[c,k]=root[k,c]
                           : Whh[(size_t)(c - 64) * 64 + k];
        b1b[j] = f2bf(v);
    } else {  // < 290816
        int j = i - 278528;
        wihb[j] = f2bf(Wih[j]);
    }
}

// ---- node input projection: h = tanh([x,u] @ Wp^T + bp) ----
__global__ __launch_bounds__(256) void k_proj(
    const float* __restrict__ x, const float* __restrict__ u,
    const float* __restrict__ Wp, const float* __restrict__ bp,
    float* __restrict__ h, unsigned short* __restrict__ hb)
{
    int idx = blockIdx.x * 256 + threadIdx.x;
    int n = idx >> 6, j = idx & 63;
    const float* wr = Wp + j * 23;
    const float* xr = x + (size_t)n * 12;
    float s = bp[j];
#pragma unroll
    for (int i = 0; i < 12; i++) s += xr[i] * wr[i];
#pragma unroll
    for (int i = 0; i < 11; i++) s += u[i] * wr[12 + i];
    float v = tanhf(s);
    h[idx] = v; hb[idx] = f2bf(v);
}

// ---- edge hidden: hid = relu(edge_attr @ We1^T + be1), stored bf16 ----
__global__ __launch_bounds__(256) void k_edge_hidden(
    const float* __restrict__ ea, const float* __restrict__ We1,
    const float* __restrict__ be1, unsigned short* __restrict__ hidb)
{
    int idx = blockIdx.x * 256 + threadIdx.x;
    int e = idx >> 6, j = idx & 63;
    float s = be1[j];
#pragma unroll
    for (int i = 0; i < 5; i++) s += ea[(size_t)e * 5 + i] * We1[j * 5 + i];
    hidb[idx] = f2bf(s > 0.f ? s : 0.f);
}

__global__ __launch_bounds__(256) void k_counts(
    const int* __restrict__ ei, float* __restrict__ counts)
{
    int i = blockIdx.x * 256 + threadIdx.x;
    if (i < N_EDGES) atomicAdd(&counts[ei[N_EDGES + i]], 1.0f);
}

// ---- ew GEMM: ew[e,c] = sum_k hid[e,k]*We2[c,k] + be2[c], bf16 out ----
// M=chunk, N=4096, K=64. 128x128 tile, 4 waves, direct global frag loads.
__global__ __launch_bounds__(256) void k_ew_gemm(
    const unsigned short* __restrict__ hidb,   // (chunk,64) bf16 (pre-offset)
    const unsigned short* __restrict__ we2b,   // (4096,64) bf16
    const float* __restrict__ be2,
    unsigned short* __restrict__ ewb)          // (chunk,4096) bf16
{
    int mtile = blockIdx.x, ntile = blockIdx.y;
    int tid = threadIdx.x, wave = tid >> 6, lane = tid & 63;
    int l15 = lane & 15, quad = lane >> 4;
    int wr = (wave >> 1) * 64, wc = (wave & 1) * 64;

    short8 a[4][2], b[4][2];
#pragma unroll
    for (int m = 0; m < 4; m++)
#pragma unroll
        for (int kk = 0; kk < 2; kk++)
            a[m][kk] = *(const short8*)(hidb + (size_t)(mtile * 128 + wr + m * 16 + l15) * 64 + kk * 32 + quad * 8);
#pragma unroll
    for (int n = 0; n < 4; n++)
#pragma unroll
        for (int kk = 0; kk < 2; kk++)
            b[n][kk] = *(const short8*)(we2b + (size_t)(ntile * 128 + wc + n * 16 + l15) * 64 + kk * 32 + quad * 8);

    float4v acc[4][4] = {};
#pragma unroll
    for (int kk = 0; kk < 2; kk++)
#pragma unroll
        for (int m = 0; m < 4; m++)
#pragma unroll
            for (int n = 0; n < 4; n++)
                acc[m][n] = __builtin_amdgcn_mfma_f32_16x16x32_bf16(a[m][kk], b[n][kk], acc[m][n], 0, 0, 0);

#pragma unroll
    for (int n = 0; n < 4; n++) {
        int col = ntile * 128 + wc + n * 16 + l15;
        float bias = be2[col];
#pragma unroll
        for (int m = 0; m < 4; m++) {
            int row = mtile * 128 + wr + m * 16 + quad * 4;
#pragma unroll
            for (int r = 0; r < 4; r++)
                ewb[(size_t)(row + r) * 4096 + col] = f2bf(acc[m][n][r] + bias);
        }
    }
}

// ---- msg: wave per edge, msg[o]=sum_h h[src,h]*ew[e,h,o]; atomic into agg[dst] ----
__global__ __launch_bounds__(256) void k_msg(
    const unsigned short* __restrict__ ewb,  // (chunk,4096)
    const float* __restrict__ h, const int* __restrict__ ei,
    float* __restrict__ agg, int eoff)
{
    int wv = blockIdx.x * 4 + (threadIdx.x >> 6);
    int lane = threadIdx.x & 63;
    int e = eoff + wv;
    int src = ei[e], dst = ei[N_EDGES + e];
    float hs = h[(size_t)src * 64 + lane];
    const unsigned short* row = ewb + (size_t)wv * 4096;

    float acc[8] = {0, 0, 0, 0, 0, 0, 0, 0};
#pragma unroll
    for (int it = 0; it < 8; it++) {
        uint4 v = *(const uint4*)(row + it * 512 + lane * 8);  // 8 bf16
        float hsv = __shfl(hs, it * 8 + (lane >> 3), 64);      // h[src, hidx]
        acc[0] += hsv * bf2f((unsigned short)(v.x & 0xffff));
        acc[1] += hsv * bf2f((unsigned short)(v.x >> 16));
        acc[2] += hsv * bf2f((unsigned short)(v.y & 0xffff));
        acc[3] += hsv * bf2f((unsigned short)(v.y >> 16));
        acc[4] += hsv * bf2f((unsigned short)(v.z & 0xffff));
        acc[5] += hsv * bf2f((unsigned short)(v.z >> 16));
        acc[6] += hsv * bf2f((unsigned short)(v.w & 0xffff));
        acc[7] += hsv * bf2f((unsigned short)(v.w >> 16));
    }
    // reduce over lanes sharing (lane&7): combine bits 3..5
#pragma unroll
    for (int d = 8; d < 64; d <<= 1)
#pragma unroll
        for (int j = 0; j < 8; j++) acc[j] += __shfl_xor(acc[j], d, 64);
    if (lane < 8) {
        float* ap = agg + (size_t)dst * 64 + lane * 8;
#pragma unroll
        for (int j = 0; j < 8; j++) atomicAdd(ap + j, acc[j]);
    }
}

// ---- node A: T = h @ [rootT;Whh]^T -> m=relu(agg/cnt+rt+conv_b) (bf16), gh=..+bhh ----
__global__ __launch_bounds__(256) void k_node_a(
    const unsigned short* __restrict__ hb, const unsigned short* __restrict__ b1b,
    const float* __restrict__ agg, const float* __restrict__ counts,
    const float* __restrict__ conv_b, const float* __restrict__ bhh,
    unsigned short* __restrict__ mb, float* __restrict__ gh)
{
    int mtile = blockIdx.x, ntile = blockIdx.y;  // ntile<2
    int tid = threadIdx.x, wave = tid >> 6, lane = tid & 63;
    int l15 = lane & 15, quad = lane >> 4;
    int wr = (wave >> 1) * 64, wc = (wave & 1) * 64;

    short8 a[4][2], b[4][2];
#pragma unroll
    for (int m = 0; m < 4; m++)
#pragma unroll
        for (int kk = 0; kk < 2; kk++)
            a[m][kk] = *(const short8*)(hb + (size_t)(mtile * 128 + wr + m * 16 + l15) * 64 + kk * 32 + quad * 8);
#pragma unroll
    for (int n = 0; n < 4; n++)
#pragma unroll
        for (int kk = 0; kk < 2; kk++)
            b[n][kk] = *(const short8*)(b1b + (size_t)(ntile * 128 + wc + n * 16 + l15) * 64 + kk * 32 + quad * 8);

    float4v acc[4][4] = {};
#pragma unroll
    for (int kk = 0; kk < 2; kk++)
#pragma unroll
        for (int m = 0; m < 4; m++)
#pragma unroll
            for (int n = 0; n < 4; n++)
                acc[m][n] = __builtin_amdgcn_mfma_f32_16x16x32_bf16(a[m][kk], b[n][kk], acc[m][n], 0, 0, 0);

#pragma unroll
    for (int n = 0; n < 4; n++) {
        int c = ntile * 128 + wc + n * 16 + l15;  // wave-uniform branch below
#pragma unroll
        for (int m = 0; m < 4; m++) {
            int rowb = mtile * 128 + wr + m * 16 + quad * 4;
#pragma unroll
            for (int r = 0; r < 4; r++) {
                int node = rowb + r;
                float v = acc[m][n][r];
                if (c < 64) {
                    float cnt = counts[node]; if (cnt < 1.f) cnt = 1.f;
                    float mv = agg[(size_t)node * 64 + c] / cnt + v + conv_b[c];
                    mb[(size_t)node * 64 + c] = f2bf(mv > 0.f ? mv : 0.f);
                } else {
                    gh[(size_t)node * 192 + (c - 64)] = v + bhh[c - 64];
                }
            }
        }
    }
}

// ---- node B: gi = m @ Wih^T; GRU gates; h update (in place, fp32 + bf16 copy) ----
__global__ __launch_bounds__(256) void k_node_b(
    const unsigned short* __restrict__ mb, const unsigned short* __restrict__ wihb,
    const float* __restrict__ gh, const float* __restrict__ bih,
    float* __restrict__ h, unsigned short* __restrict__ hb)
{
    int mtile = blockIdx.x;
    int tid = threadIdx.x, wave = tid >> 6, lane = tid & 63;
    int l15 = lane & 15, quad = lane >> 4;
    int jj = wave * 16 + l15;  // each wave owns cols {jj, 64+jj, 128+jj}

    short8 b[3][2];
#pragma unroll
    for (int g = 0; g < 3; g++)
#pragma unroll
        for (int kk = 0; kk < 2; kk++)
            b[g][kk] = *(const short8*)(wihb + (size_t)(g * 64 + jj) * 64 + kk * 32 + quad * 8);
    float bih_r = bih[jj], bih_z = bih[64 + jj], bih_n = bih[128 + jj];

#pragma unroll
    for (int m = 0; m < 8; m++) {
        int rowb = mtile * 128 + m * 16;
        short8 a[2];
#pragma unroll
        for (int kk = 0; kk < 2; kk++)
            a[kk] = *(const short8*)(mb + (size_t)(rowb + l15) * 64 + kk * 32 + quad * 8);
        float4v acc[3] = {};
#pragma unroll
        for (int kk = 0; kk < 2; kk++)
#pragma unroll
            for (int g = 0; g < 3; g++)
                acc[g] = __builtin_amdgcn_mfma_f32_16x16x32_bf16(a[kk], b[g][kk], acc[g], 0, 0, 0);
#pragma unroll
        for (int r = 0; r < 4; r++) {
            int node = rowb + quad * 4 + r;
            float ghr = gh[(size_t)node * 192 + jj];
            float ghz = gh[(size_t)node * 192 + 64 + jj];
            float ghn = gh[(size_t)node * 192 + 128 + jj];
            float rr = 1.f / (1.f + __expf(-(acc[0][r] + bih_r + ghr)));
            float zz = 1.f / (1.f + __expf(-(acc[1][r] + bih_z + ghz)));
            float ng = tanhf(acc[2][r] + bih_n + rr * ghn);
            float ho = h[(size_t)node * 64 + jj];
            float hn = (1.f - zz) * ng + zz * ho;
            h[(size_t)node * 64 + jj] = hn;
            hb[(size_t)node * 64 + jj] = f2bf(hn);
        }
    }
}

// ---- decoder: wave per edge, weights staged in LDS (fp32) ----
__global__ __launch_bounds__(256) void k_decoder(
    const float* __restrict__ h, const int* __restrict__ ei, const float* __restrict__ ea,
    const float* __restrict__ Wd1, const float* __restrict__ bd1,
    const float* __restrict__ Wd2, const float* __restrict__ bd2,
    const float* __restrict__ Wd3, const float* __restrict__ bd3,
    float* __restrict__ out)
{
    __shared__ float w1[64 * 133], w2[32 * 65], w3[4 * 33], b1[64], b2[32], b3[4];
    __shared__ float ein[4][144], d1b[4][64], d2b[4][32];
    int tid = threadIdx.x;
    for (int i = tid; i < 64 * 133; i += 256) w1[i] = Wd1[i];
    for (int i = tid; i < 2048; i += 256) w2[(i >> 6) * 65 + (i & 63)] = Wd2[i];
    if (tid < 128) w3[(tid >> 5) * 33 + (tid & 31)] = Wd3[tid];
    if (tid < 64) b1[tid] = bd1[tid];
    if (tid < 32) b2[tid] = bd2[tid];
    if (tid < 4)  b3[tid] = bd3[tid];
    __syncthreads();
    int wave = tid >> 6, lane = tid & 63;
    for (int it = 0; it < 16; it++) {
        int e = blockIdx.x * 64 + it * 4 + wave;
        int src = ei[e], dst = ei[N_EDGES + e];
        ein[wave][lane]      = h[(size_t)src * 64 + lane];
        ein[wave][64 + lane] = h[(size_t)dst * 64 + lane];
        if (lane < 5) ein[wave][128 + lane] = ea[(size_t)e * 5 + lane];
        __syncthreads();
        {
            float s = b1[lane];
            for (int k = 0; k < 133; k++) s += w1[lane * 133 + k] * ein[wave][k];
            d1b[wave][lane] = s > 0.f ? s : 0.f;
        }
        __syncthreads();
        if (lane < 32) {
            float s = b2[lane];
            for (int k = 0; k < 64; k++) s += w2[lane * 65 + k] * d1b[wave][k];
            d2b[wave][lane] = s > 0.f ? s : 0.f;
        }
        __syncthreads();
        if (lane < 4) {
            float s = b3[lane];
            for (int k = 0; k < 32; k++) s += w3[lane * 33 + k] * d2b[wave][k];
            out[(size_t)e * 4 + lane] = s;
        }
        __syncthreads();
    }
}

extern "C" void kernel_launch(void* const* d_in, const int* in_sizes, int n_in,
                              void* d_out, int out_size, void* d_ws, size_t ws_size,
                              hipStream_t stream)
{
    const float* x      = (const float*)d_in[0];
    const int*   ei     = (const int*)d_in[1];
    const float* ea     = (const float*)d_in[2];
    const float* u      = (const float*)d_in[3];
    const float* Wp     = (const float*)d_in[4];
    const float* bp     = (const float*)d_in[5];
    const float* We1    = (const float*)d_in[6];
    const float* be1    = (const float*)d_in[7];
    const float* We2    = (const float*)d_in[8];
    const float* be2    = (const float*)d_in[9];
    const float* root   = (const float*)d_in[10];
    const float* conv_b = (const float*)d_in[11];
    const float* Wih    = (const float*)d_in[12];
    const float* bih    = (const float*)d_in[13];
    const float* Whh    = (const float*)d_in[14];
    const float* bhh    = (const float*)d_in[15];
    const float* Wd1    = (const float*)d_in[16];
    const float* bd1    = (const float*)d_in[17];
    const float* Wd2    = (const float*)d_in[18];
    const float* bd2    = (const float*)d_in[19];
    const float* Wd3    = (const float*)d_in[20];
    const float* bd3    = (const float*)d_in[21];
    float* out = (float*)d_out;

    char* ws = (char*)d_ws;
    size_t off = 0;
    auto take = [&](size_t bytes) -> char* {
        char* p = ws + off; off = (off + bytes + 255) & ~(size_t)255; return p;
    };
    float*          h     = (float*)take((size_t)N_NODES * 64 * 4);
    unsigned short* hb    = (unsigned short*)take((size_t)N_NODES * 64 * 2);
    unsigned short* hidb  = (unsigned short*)take((size_t)N_EDGES * 64 * 2);
    float*          agg   = (float*)take((size_t)N_NODES * 64 * 4);
    float*          cnts  = (float*)take((size_t)N_NODES * 4);
    float*          gh    = (float*)take((size_t)N_NODES * 192 * 4);
    unsigned short* mb    = (unsigned short*)take((size_t)N_NODES * 64 * 2);
    unsigned short* we2b  = (unsigned short*)take((size_t)4096 * 64 * 2);
    unsigned short* b1b   = (unsigned short*)take((size_t)256 * 64 * 2);
    unsigned short* wihb  = (unsigned short*)take((size_t)192 * 64 * 2);
    size_t base_need = off;
    unsigned short* ewb = (unsigned short*)(ws + base_need);

    size_t avail = ws_size > base_need ? ws_size - base_need : 0;
    size_t full  = (size_t)N_EDGES * 4096 * 2;  // 256 MB
    int chunk = N_EDGES;
    if (avail < full) {
        chunk = (int)(avail / ((size_t)4096 * 2));
        chunk &= ~127;
        if (chunk < 128) chunk = 128;
        if (chunk > N_EDGES) chunk = N_EDGES;
    }
    bool resident = (chunk == N_EDGES);

    hipMemsetAsync(cnts, 0, (size_t)N_NODES * 4, stream);
    k_prep<<<1136, 256, 0, stream>>>(We2, root, Whh, Wih, we2b, b1b, wihb);
    k_proj<<<8192, 256, 0, stream>>>(x, u, Wp, bp, h, hb);
    k_edge_hidden<<<8192, 256, 0, stream>>>(ea, We1, be1, hidb);
    k_counts<<<128, 256, 0, stream>>>(ei, cnts);

    if (resident) {
        dim3 g(N_EDGES / 128, 32);
        k_ew_gemm<<<g, 256, 0, stream>>>(hidb, we2b, be2, ewb);
    }
    for (int s = 0; s < STEPS; s++) {
        hipMemsetAsync(agg, 0, (size_t)N_NODES * 64 * 4, stream);
        if (resident) {
            k_msg<<<N_EDGES / 4, 256, 0, stream>>>(ewb, h, ei, agg, 0);
        } else {
            for (int eoff = 0; eoff < N_EDGES; eoff += chunk) {
                int ecnt = (N_EDGES - eoff) < chunk ? (N_EDGES - eoff) : chunk;
                dim3 g(ecnt / 128, 32);
                k_ew_gemm<<<g, 256, 0, stream>>>(hidb + (size_t)eoff * 64, we2b, be2, ewb);
                k_msg<<<ecnt / 4, 256, 0, stream>>>(ewb, h, ei, agg, eoff);
            }
        }
        k_node_a<<<dim3(N_NODES / 128, 2), 256, 0, stream>>>(hb, b1b, agg, cnts, conv_b, bhh, mb, gh);
        k_node_b<<<N_NODES / 128, 256, 0, stream>>>(mb, wihb, gh, bih, h, hb);
    }
    k_decoder<<<512, 256, 0, stream>>>(h, ei, ea, Wd1, bd1, Wd2, bd2, Wd3, bd3, out);
}

// Round 2
// 752.385 us; speedup vs baseline: 1.2201x; 1.2201x over previous
//
#include <hip/hip_runtime.h>
#include <hip/hip_bf16.h>
#include <stdint.h>

// MPNN latency predictor, MI355X — round 2.
// Key change vs R1: NO ew=(E,64,64) materialization. msg is computed as a
// fused bilinear GEMM: msg[e,o] = sum_{k,h} hid[e,k]*h[src,h]*We2[h*64+o,k]
//   = A(e,:) @ W2T^T, A generated in-register from outer(hid[e], h[src]),
// K = 65*64 = 4160 (bias folded via hid row 64 == 1.0).
// W2T (64 x 4160 bf16, 532 KB) is loop-invariant and L2-resident.

#define N_NODES 32768
#define N_EDGES 32768
#define STEPS 3
#define KTOT 4160   // 65*64

typedef __attribute__((ext_vector_type(8))) short short8;   // 8 bf16 = 4 VGPRs
typedef __attribute__((ext_vector_type(4))) float float4v;  // MFMA C/D

__device__ __forceinline__ float bf2f(unsigned short u) {
    union { unsigned int i; float f; } v; v.i = ((unsigned int)u) << 16; return v.f;
}
__device__ __forceinline__ unsigned short f2bf(float f) {  // RNE
    union { float f; unsigned int i; } v; v.f = f;
    unsigned int x = v.i;
    return (unsigned short)((x + 0x7fffu + ((x >> 16) & 1u)) >> 16);
}

// ---- prep: bf16 [rootT;Whh] and Wih ----
__global__ __launch_bounds__(256) void k_prep(
    const float* __restrict__ root, const float* __restrict__ Whh,
    const float* __restrict__ Wih,
    unsigned short* __restrict__ b1b, unsigned short* __restrict__ wihb)
{
    int i = blockIdx.x * 256 + threadIdx.x;
    if (i < 16384) {
        int c = i >> 6, k = i & 63;
        float v = (c < 64) ? root[k * 64 + c]            // rootT: B[c,k]=root[k,c]
                           : Whh[(size_t)(c - 64) * 64 + k];
        b1b[i] = f2bf(v);
    } else {  // < 28672
        int j = i - 16384;
        wihb[j] = f2bf(Wih[j]);
    }
}

// ---- prep: W2T[o][k] ; k = kk*64+hh -> We2[(hh*64+o)*64+kk], tail = be2 ----
__global__ __launch_bounds__(256) void k_prep_w2t(
    const float* __restrict__ We2, const float* __restrict__ be2,
    unsigned short* __restrict__ w2t)
{
    int k = blockIdx.x * 256 + threadIdx.x;
    int o = blockIdx.y;
    if (k >= KTOT) return;
    float v;
    if (k < 4096) {
        int kk = k >> 6, hh = k & 63;
        v = We2[((size_t)(hh * 64 + o)) * 64 + kk];
    } else {
        v = be2[(size_t)(k - 4096) * 64 + o];
    }
    w2t[(size_t)o * KTOT + k] = f2bf(v);
}

// ---- node input projection: h = tanh([x,u] @ Wp^T + bp) ----
__global__ __launch_bounds__(256) void k_proj(
    const float* __restrict__ x, const float* __restrict__ u,
    const float* __restrict__ Wp, const float* __restrict__ bp,
    float* __restrict__ h, unsigned short* __restrict__ hb)
{
    int idx = blockIdx.x * 256 + threadIdx.x;
    int n = idx >> 6, j = idx & 63;
    const float* wr = Wp + j * 23;
    const float* xr = x + (size_t)n * 12;
    float s = bp[j];
#pragma unroll
    for (int i = 0; i < 12; i++) s += xr[i] * wr[i];
#pragma unroll
    for (int i = 0; i < 11; i++) s += u[i] * wr[12 + i];
    float v = tanhf(s);
    h[idx] = v; hb[idx] = f2bf(v);
}

// ---- edge hidden, transposed: hidT[j*E + e], row 64 = 1.0 (bias fold) ----
__global__ __launch_bounds__(256) void k_edge_hidden_T(
    const float* __restrict__ ea, const float* __restrict__ We1,
    const float* __restrict__ be1, unsigned short* __restrict__ hidT)
{
    int t = blockIdx.x * 256 + threadIdx.x;  // t < 65*32768
    int j = t >> 15, e = t & 32767;
    if (j == 64) { hidT[t] = 0x3F80; return; }  // bf16 1.0
    float s = be1[j];
#pragma unroll
    for (int i = 0; i < 5; i++) s += ea[(size_t)e * 5 + i] * We1[j * 5 + i];
    hidT[t] = f2bf(s > 0.f ? s : 0.f);
}

__global__ __launch_bounds__(256) void k_counts(
    const int* __restrict__ ei, float* __restrict__ counts)
{
    int i = blockIdx.x * 256 + threadIdx.x;
    if (i < N_EDGES) atomicAdd(&counts[ei[N_EDGES + i]], 1.0f);
}

// ---- fused msg GEMM: A generated in-register from outer(hid[e], h[src]) ----
// Block = 4 waves: (wave>>1) picks 16-edge m-frag, (wave&1) picks K-half.
// Partial sums merge via the atomicAdd scatter epilogue (agg pre-zeroed).
__global__ __launch_bounds__(256) void k_msg_fused(
    const unsigned short* __restrict__ hidT,  // (65, E) bf16
    const unsigned short* __restrict__ hb,    // (N, 64) bf16
    const unsigned short* __restrict__ w2t,   // (64, 4160) bf16
    const int* __restrict__ ei,
    float* __restrict__ agg)
{
    int tid = threadIdx.x, wave = tid >> 6, lane = tid & 63;
    int l15 = lane & 15, quad = lane >> 4;
    int mf = wave >> 1, kh = wave & 1;
    int ebase = blockIdx.x * 32 + mf * 16;
    int e_a = ebase + l15;                 // A-row edge for this lane
    int src = ei[e_a];

    short8 hs[2];
    hs[0] = *(const short8*)(hb + (size_t)src * 64 + quad * 8);
    hs[1] = *(const short8*)(hb + (size_t)src * 64 + 32 + quad * 8);

    float4v acc[4] = {};
    int kb0 = kh * 65;
    for (int kb = kb0; kb < kb0 + 65; kb++) {
        int kk = kb >> 1, half = kb & 1;
        float hv = bf2f(hidT[kk * N_EDGES + e_a]);
        short8 hvec = hs[half];
        short8 a;
#pragma unroll
        for (int j = 0; j < 8; j++) a[j] = (short)f2bf(hv * bf2f((unsigned short)hvec[j]));
#pragma unroll
        for (int nf = 0; nf < 4; nf++) {
            short8 b = *(const short8*)(w2t + (size_t)(nf * 16 + l15) * KTOT + kb * 32 + quad * 8);
            acc[nf] = __builtin_amdgcn_mfma_f32_16x16x32_bf16(a, b, acc[nf], 0, 0, 0);
        }
    }

    // epilogue: C row = quad*4+r (edge), col = nf*16+l15; scatter-add to dst
    int dsts[4];
#pragma unroll
    for (int r = 0; r < 4; r++) dsts[r] = ei[N_EDGES + ebase + quad * 4 + r];
#pragma unroll
    for (int nf = 0; nf < 4; nf++)
#pragma unroll
        for (int r = 0; r < 4; r++)
            atomicAdd(agg + (size_t)dsts[r] * 64 + nf * 16 + l15, acc[nf][r]);
}

// ---- node A: T = h @ [rootT;Whh]^T -> m=relu(agg/cnt+rt+conv_b) (bf16), gh=..+bhh ----
__global__ __launch_bounds__(256) void k_node_a(
    const unsigned short* __restrict__ hb, const unsigned short* __restrict__ b1b,
    const float* __restrict__ agg, const float* __restrict__ counts,
    const float* __restrict__ conv_b, const float* __restrict__ bhh,
    unsigned short* __restrict__ mb, float* __restrict__ gh)
{
    int mtile = blockIdx.x, ntile = blockIdx.y;  // ntile<2
    int tid = threadIdx.x, wave = tid >> 6, lane = tid & 63;
    int l15 = lane & 15, quad = lane >> 4;
    int wr = (wave >> 1) * 64, wc = (wave & 1) * 64;

    short8 a[4][2], b[4][2];
#pragma unroll
    for (int m = 0; m < 4; m++)
#pragma unroll
        for (int kk = 0; kk < 2; kk++)
            a[m][kk] = *(const short8*)(hb + (size_t)(mtile * 128 + wr + m * 16 + l15) * 64 + kk * 32 + quad * 8);
#pragma unroll
    for (int n = 0; n < 4; n++)
#pragma unroll
        for (int kk = 0; kk < 2; kk++)
            b[n][kk] = *(const short8*)(b1b + (size_t)(ntile * 128 + wc + n * 16 + l15) * 64 + kk * 32 + quad * 8);

    float4v acc[4][4] = {};
#pragma unroll
    for (int kk = 0; kk < 2; kk++)
#pragma unroll
        for (int m = 0; m < 4; m++)
#pragma unroll
            for (int n = 0; n < 4; n++)
                acc[m][n] = __builtin_amdgcn_mfma_f32_16x16x32_bf16(a[m][kk], b[n][kk], acc[m][n], 0, 0, 0);

#pragma unroll
    for (int n = 0; n < 4; n++) {
        int c = ntile * 128 + wc + n * 16 + l15;  // wave-uniform branch below
#pragma unroll
        for (int m = 0; m < 4; m++) {
            int rowb = mtile * 128 + wr + m * 16 + quad * 4;
#pragma unroll
            for (int r = 0; r < 4; r++) {
                int node = rowb + r;
                float v = acc[m][n][r];
                if (c < 64) {
                    float cnt = counts[node]; if (cnt < 1.f) cnt = 1.f;
                    float mv = agg[(size_t)node * 64 + c] / cnt + v + conv_b[c];
                    mb[(size_t)node * 64 + c] = f2bf(mv > 0.f ? mv : 0.f);
                } else {
                    gh[(size_t)node * 192 + (c - 64)] = v + bhh[c - 64];
                }
            }
        }
    }
}

// ---- node B: gi = m @ Wih^T; GRU gates; h update (fp32 + bf16 copy) ----
__global__ __launch_bounds__(256) void k_node_b(
    const unsigned short* __restrict__ mb, const unsigned short* __restrict__ wihb,
    const float* __restrict__ gh, const float* __restrict__ bih,
    float* __restrict__ h, unsigned short* __restrict__ hb)
{
    int mtile = blockIdx.x;
    int tid = threadIdx.x, wave = tid >> 6, lane = tid & 63;
    int l15 = lane & 15, quad = lane >> 4;
    int jj = wave * 16 + l15;  // each wave owns cols {jj, 64+jj, 128+jj}

    short8 b[3][2];
#pragma unroll
    for (int g = 0; g < 3; g++)
#pragma unroll
        for (int kk = 0; kk < 2; kk++)
            b[g][kk] = *(const short8*)(wihb + (size_t)(g * 64 + jj) * 64 + kk * 32 + quad * 8);
    float bih_r = bih[jj], bih_z = bih[64 + jj], bih_n = bih[128 + jj];

#pragma unroll
    for (int m = 0; m < 8; m++) {
        int rowb = mtile * 128 + m * 16;
        short8 a[2];
#pragma unroll
        for (int kk = 0; kk < 2; kk++)
            a[kk] = *(const short8*)(mb + (size_t)(rowb + l15) * 64 + kk * 32 + quad * 8);
        float4v acc[3] = {};
#pragma unroll
        for (int kk = 0; kk < 2; kk++)
#pragma unroll
            for (int g = 0; g < 3; g++)
                acc[g] = __builtin_amdgcn_mfma_f32_16x16x32_bf16(a[kk], b[g][kk], acc[g], 0, 0, 0);
#pragma unroll
        for (int r = 0; r < 4; r++) {
            int node = rowb + quad * 4 + r;
            float ghr = gh[(size_t)node * 192 + jj];
            float ghz = gh[(size_t)node * 192 + 64 + jj];
            float ghn = gh[(size_t)node * 192 + 128 + jj];
            float rr = 1.f / (1.f + __expf(-(acc[0][r] + bih_r + ghr)));
            float zz = 1.f / (1.f + __expf(-(acc[1][r] + bih_z + ghz)));
            float ng = tanhf(acc[2][r] + bih_n + rr * ghn);
            float ho = h[(size_t)node * 64 + jj];
            float hn = (1.f - zz) * ng + zz * ho;
            h[(size_t)node * 64 + jj] = hn;
            hb[(size_t)node * 64 + jj] = f2bf(hn);
        }
    }
}

// ---- decoder: wave per edge, weights staged in LDS (fp32) ----
__global__ __launch_bounds__(256) void k_decoder(
    const float* __restrict__ h, const int* __restrict__ ei, const float* __restrict__ ea,
    const float* __restrict__ Wd1, const float* __restrict__ bd1,
    const float* __restrict__ Wd2, const float* __restrict__ bd2,
    const float* __restrict__ Wd3, const float* __restrict__ bd3,
    float* __restrict__ out)
{
    __shared__ float w1[64 * 133], w2[32 * 65], w3[4 * 33], b1[64], b2[32], b3[4];
    __shared__ float ein[4][144], d1b[4][64], d2b[4][32];
    int tid = threadIdx.x;
    for (int i = tid; i < 64 * 133; i += 256) w1[i] = Wd1[i];
    for (int i = tid; i < 2048; i += 256) w2[(i >> 6) * 65 + (i & 63)] = Wd2[i];
    if (tid < 128) w3[(tid >> 5) * 33 + (tid & 31)] = Wd3[tid];
    if (tid < 64) b1[tid] = bd1[tid];
    if (tid < 32) b2[tid] = bd2[tid];
    if (tid < 4)  b3[tid] = bd3[tid];
    __syncthreads();
    int wave = tid >> 6, lane = tid & 63;
    for (int it = 0; it < 16; it++) {
        int e = blockIdx.x * 64 + it * 4 + wave;
        int src = ei[e], dst = ei[N_EDGES + e];
        ein[wave][lane]      = h[(size_t)src * 64 + lane];
        ein[wave][64 + lane] = h[(size_t)dst * 64 + lane];
        if (lane < 5) ein[wave][128 + lane] = ea[(size_t)e * 5 + lane];
        __syncthreads();
        {
            float s = b1[lane];
            for (int k = 0; k < 133; k++) s += w1[lane * 133 + k] * ein[wave][k];
            d1b[wave][lane] = s > 0.f ? s : 0.f;
        }
        __syncthreads();
        if (lane < 32) {
            float s = b2[lane];
            for (int k = 0; k < 64; k++) s += w2[lane * 65 + k] * d1b[wave][k];
            d2b[wave][lane] = s > 0.f ? s : 0.f;
        }
        __syncthreads();
        if (lane < 4) {
            float s = b3[lane];
            for (int k = 0; k < 32; k++) s += w3[lane * 33 + k] * d2b[wave][k];
            out[(size_t)e * 4 + lane] = s;
        }
        __syncthreads();
    }
}

extern "C" void kernel_launch(void* const* d_in, const int* in_sizes, int n_in,
                              void* d_out, int out_size, void* d_ws, size_t ws_size,
                              hipStream_t stream)
{
    const float* x      = (const float*)d_in[0];
    const int*   ei     = (const int*)d_in[1];
    const float* ea     = (const float*)d_in[2];
    const float* u      = (const float*)d_in[3];
    const float* Wp     = (const float*)d_in[4];
    const float* bp     = (const float*)d_in[5];
    const float* We1    = (const float*)d_in[6];
    const float* be1    = (const float*)d_in[7];
    const float* We2    = (const float*)d_in[8];
    const float* be2    = (const float*)d_in[9];
    const float* root   = (const float*)d_in[10];
    const float* conv_b = (const float*)d_in[11];
    const float* Wih    = (const float*)d_in[12];
    const float* bih    = (const float*)d_in[13];
    const float* Whh    = (const float*)d_in[14];
    const float* bhh    = (const float*)d_in[15];
    const float* Wd1    = (const float*)d_in[16];
    const float* bd1    = (const float*)d_in[17];
    const float* Wd2    = (const float*)d_in[18];
    const float* bd2    = (const float*)d_in[19];
    const float* Wd3    = (const float*)d_in[20];
    const float* bd3    = (const float*)d_in[21];
    float* out = (float*)d_out;

    char* ws = (char*)d_ws;
    size_t off = 0;
    auto take = [&](size_t bytes) -> char* {
        char* p = ws + off; off = (off + bytes + 255) & ~(size_t)255; return p;
    };
    float*          h     = (float*)take((size_t)N_NODES * 64 * 4);
    unsigned short* hb    = (unsigned short*)take((size_t)N_NODES * 64 * 2);
    unsigned short* hidT  = (unsigned short*)take((size_t)65 * N_EDGES * 2);
    float*          agg   = (float*)take((size_t)N_NODES * 64 * 4);
    float*          cnts  = (float*)take((size_t)N_NODES * 4);
    float*          gh    = (float*)take((size_t)N_NODES * 192 * 4);
    unsigned short* mb    = (unsigned short*)take((size_t)N_NODES * 64 * 2);
    unsigned short* w2t   = (unsigned short*)take((size_t)64 * KTOT * 2);
    unsigned short* b1b   = (unsigned short*)take((size_t)256 * 64 * 2);
    unsigned short* wihb  = (unsigned short*)take((size_t)192 * 64 * 2);
    (void)ws_size;

    hipMemsetAsync(cnts, 0, (size_t)N_NODES * 4, stream);
    k_prep<<<112, 256, 0, stream>>>(root, Whh, Wih, b1b, wihb);
    k_prep_w2t<<<dim3(17, 64), 256, 0, stream>>>(We2, be2, w2t);
    k_proj<<<8192, 256, 0, stream>>>(x, u, Wp, bp, h, hb);
    k_edge_hidden_T<<<8320, 256, 0, stream>>>(ea, We1, be1, hidT);
    k_counts<<<128, 256, 0, stream>>>(ei, cnts);

    for (int s = 0; s < STEPS; s++) {
        hipMemsetAsync(agg, 0, (size_t)N_NODES * 64 * 4, stream);
        k_msg_fused<<<N_EDGES / 32, 256, 0, stream>>>(hidT, hb, w2t, ei, agg);
        k_node_a<<<dim3(N_NODES / 128, 2), 256, 0, stream>>>(hb, b1b, agg, cnts, conv_b, bhh, mb, gh);
        k_node_b<<<N_NODES / 128, 256, 0, stream>>>(mb, wihb, gh, bih, h, hb);
    }
    k_decoder<<<512, 256, 0, stream>>>(h, ei, ea, Wd1, bd1, Wd2, bd2, Wd3, bd3, out);
}

// Round 3
// 623.407 us; speedup vs baseline: 1.4725x; 1.2069x over previous
//
#include <hip/hip_runtime.h>
#include <hip/hip_bf16.h>
#include <stdint.h>

// MPNN latency predictor, MI355X — round 3.
// vs R2: (1) k_msg_fused A-generation rewritten: static unroll, register-held
// hid row, f32-preconverted h[src], 2-per-perm bf16 packing (~2.5 VALU/elt vs
// ~10); full-K per wave (no dup atomics). (2) node_a+node_b fused into k_node:
// m via LDS, gi+gh as one [m|h]@[Wih|Whh]^T GEMM (N=256), gh/mb HBM buffers
// eliminated, agg zeroing folded into epilogue.

#define N_NODES 32768
#define N_EDGES 32768
#define STEPS 3
#define KTOT 4160   // 65*64

typedef __attribute__((ext_vector_type(8))) short short8;   // 8 bf16 = 4 VGPRs
typedef __attribute__((ext_vector_type(4))) float float4v;  // MFMA C/D

__device__ __forceinline__ float bf2f(unsigned short u) {
    union { unsigned int i; float f; } v; v.i = ((unsigned int)u) << 16; return v.f;
}
__device__ __forceinline__ unsigned short f2bf(float f) {  // RNE
    union { float f; unsigned int i; } v; v.f = f;
    unsigned int x = v.i;
    return (unsigned short)((x + 0x7fffu + ((x >> 16) & 1u)) >> 16);
}
__device__ __forceinline__ unsigned int fbits(float f) {
    union { float f; unsigned int i; } v; v.f = f; return v.i;
}

// pack 8 products hv*hf[j] into a bf16x8 A-frag: round-half-up + v_perm pack
__device__ __forceinline__ short8 packA(float hv, const float* hf) {
    union { short8 v; unsigned int u[4]; } r;
#pragma unroll
    for (int p = 0; p < 4; p++) {
        unsigned int p0 = fbits(hv * hf[2 * p]) + 0x8000u;
        unsigned int p1 = fbits(hv * hf[2 * p + 1]) + 0x8000u;
        r.u[p] = __builtin_amdgcn_perm(p1, p0, 0x07060302u);  // {hi16(p0), hi16(p1)}
    }
    return r.v;
}

// ---- prep: rootT (64x64) and wcomb (256x128) bf16 ----
// wcomb rows: [0,64)=r-gate [Wih_r|Whh_r]; [64,128)=z; [128,192)=[Wih_n|0];
//             [192,256)=[0|Whh_n]
__global__ __launch_bounds__(256) void k_prep(
    const float* __restrict__ root, const float* __restrict__ Wih,
    const float* __restrict__ Whh,
    unsigned short* __restrict__ rootT_b, unsigned short* __restrict__ wcomb)
{
    int i = blockIdx.x * 256 + threadIdx.x;
    if (i < 4096) {
        int c = i >> 6, k = i & 63;
        rootT_b[i] = f2bf(root[k * 64 + c]);
    } else if (i < 4096 + 32768) {
        int j = i - 4096;
        int cp = j >> 7, k = j & 127;
        float v;
        if (cp < 128)      v = (k < 64) ? Wih[cp * 64 + k] : Whh[cp * 64 + (k - 64)];
        else if (cp < 192) v = (k < 64) ? Wih[(128 + (cp - 128)) * 64 + k] : 0.f;
        else               v = (k < 64) ? 0.f : Whh[(128 + (cp - 192)) * 64 + (k - 64)];
        wcomb[j] = f2bf(v);
    }
}

// ---- prep: W2T[o][k] ; k = kk*64+hh -> We2[(hh*64+o)*64+kk], tail = be2 ----
__global__ __launch_bounds__(256) void k_prep_w2t(
    const float* __restrict__ We2, const float* __restrict__ be2,
    unsigned short* __restrict__ w2t)
{
    int k = blockIdx.x * 256 + threadIdx.x;
    int o = blockIdx.y;
    if (k >= KTOT) return;
    float v;
    if (k < 4096) {
        int kk = k >> 6, hh = k & 63;
        v = We2[((size_t)(hh * 64 + o)) * 64 + kk];
    } else {
        v = be2[(size_t)(k - 4096) * 64 + o];
    }
    w2t[(size_t)o * KTOT + k] = f2bf(v);
}

// ---- node input projection: h = tanh([x,u] @ Wp^T + bp) ----
__global__ __launch_bounds__(256) void k_proj(
    const float* __restrict__ x, const float* __restrict__ u,
    const float* __restrict__ Wp, const float* __restrict__ bp,
    float* __restrict__ h, unsigned short* __restrict__ hb)
{
    int idx = blockIdx.x * 256 + threadIdx.x;
    int n = idx >> 6, j = idx & 63;
    const float* wr = Wp + j * 23;
    const float* xr = x + (size_t)n * 12;
    float s = bp[j];
#pragma unroll
    for (int i = 0; i < 12; i++) s += xr[i] * wr[i];
#pragma unroll
    for (int i = 0; i < 11; i++) s += u[i] * wr[12 + i];
    float v = tanhf(s);
    h[idx] = v; hb[idx] = f2bf(v);
}

// ---- edge hidden (row-major, stride 64): hid = relu(ea @ We1^T + be1) ----
__global__ __launch_bounds__(256) void k_edge_hidden(
    const float* __restrict__ ea, const float* __restrict__ We1,
    const float* __restrict__ be1, unsigned short* __restrict__ hidb)
{
    int idx = blockIdx.x * 256 + threadIdx.x;
    int e = idx >> 6, j = idx & 63;
    float s = be1[j];
#pragma unroll
    for (int i = 0; i < 5; i++) s += ea[(size_t)e * 5 + i] * We1[j * 5 + i];
    hidb[idx] = f2bf(s > 0.f ? s : 0.f);
}

__global__ __launch_bounds__(256) void k_counts(
    const int* __restrict__ ei, float* __restrict__ counts)
{
    int i = blockIdx.x * 256 + threadIdx.x;
    if (i < N_EDGES) atomicAdd(&counts[ei[N_EDGES + i]], 1.0f);
}

// ---- fused msg GEMM: msg[e,o] = sum_{k} A[e,k]*W2T[o,k], K=4160 ----
// A[e, kk*64+hh] = hid[e,kk]*h[src,hh] (kk=64 -> bias row, hid==1).
// Wave = 16 edges, full K. Block = 4 waves = 64 edges. atomicAdd scatter.
__global__ __launch_bounds__(256) void k_msg_fused(
    const unsigned short* __restrict__ hid,   // (E,64) bf16
    const unsigned short* __restrict__ hb,    // (N,64) bf16
    const unsigned short* __restrict__ w2t,   // (64,4160) bf16
    const int* __restrict__ ei,
    float* __restrict__ agg)
{
    int tid = threadIdx.x, wave = tid >> 6, lane = tid & 63;
    int l15 = lane & 15, quad = lane >> 4;
    int ebase = blockIdx.x * 64 + wave * 16;
    int e_a = ebase + l15;
    int src = ei[e_a];

    // hid row of this lane's edge: 64 bf16 in registers
    union { short8 v[8]; unsigned short u[64]; } hrow;
#pragma unroll
    for (int i = 0; i < 8; i++)
        hrow.v[i] = *(const short8*)(hid + (size_t)e_a * 64 + i * 8);

    // h[src] window for this lane's k-positions, f32: parity 0 -> hh=quad*8+j,
    // parity 1 -> hh=32+quad*8+j
    float hf0[8], hf1[8];
    {
        short8 h0 = *(const short8*)(hb + (size_t)src * 64 + quad * 8);
        short8 h1 = *(const short8*)(hb + (size_t)src * 64 + 32 + quad * 8);
#pragma unroll
        for (int j = 0; j < 8; j++) {
            hf0[j] = bf2f((unsigned short)h0[j]);
            hf1[j] = bf2f((unsigned short)h1[j]);
        }
    }

    const unsigned short* bbase[4];
#pragma unroll
    for (int nf = 0; nf < 4; nf++)
        bbase[nf] = w2t + (size_t)(nf * 16 + l15) * KTOT + quad * 8;

    float4v acc[4] = {};
#pragma unroll
    for (int kk = 0; kk < 65; kk++) {
        float hv = (kk < 64) ? bf2f(hrow.u[kk]) : 1.0f;
        short8 a0 = packA(hv, hf0);
        short8 a1 = packA(hv, hf1);
#pragma unroll
        for (int nf = 0; nf < 4; nf++) {
            short8 b0 = *(const short8*)(bbase[nf] + (2 * kk) * 32);
            acc[nf] = __builtin_amdgcn_mfma_f32_16x16x32_bf16(a0, b0, acc[nf], 0, 0, 0);
        }
#pragma unroll
        for (int nf = 0; nf < 4; nf++) {
            short8 b1 = *(const short8*)(bbase[nf] + (2 * kk + 1) * 32);
            acc[nf] = __builtin_amdgcn_mfma_f32_16x16x32_bf16(a1, b1, acc[nf], 0, 0, 0);
        }
    }

    // epilogue: C row = quad*4+r (edge), col = nf*16+l15; scatter-add to dst
    int dsts[4];
#pragma unroll
    for (int r = 0; r < 4; r++) dsts[r] = ei[N_EDGES + ebase + quad * 4 + r];
#pragma unroll
    for (int nf = 0; nf < 4; nf++)
#pragma unroll
        for (int r = 0; r < 4; r++)
            atomicAdd(agg + (size_t)dsts[r] * 64 + nf * 16 + l15, acc[nf][r]);
}

// ---- fused node update: T=h@rootT^T -> m (LDS) -> G=[m|h]@wcomb^T -> GRU ----
// Also zeroes agg for the next step's atomics.
__global__ __launch_bounds__(256) void k_node(
    const unsigned short* __restrict__ hb_in,
    const unsigned short* __restrict__ rootT_b,
    const unsigned short* __restrict__ wcomb,
    float* __restrict__ agg, const float* __restrict__ counts,
    const float* __restrict__ conv_b,
    const float* __restrict__ bih, const float* __restrict__ bhh,
    float* __restrict__ h, unsigned short* __restrict__ hb_out)
{
    __shared__ unsigned short m_lds[128 * 72];  // stride 72: bank-safe
    int tid = threadIdx.x, w = tid >> 6, lane = tid & 63;
    int l15 = lane & 15, quad = lane >> 4;
    int node0 = blockIdx.x * 128;
    int row0 = w * 32;

    // ---- stage 1: T = h_tile @ rootT^T (32 rows x 64 cols per wave) ----
    float4v acc1[2][4] = {};
    {
        short8 a1[2][2], b1[4][2];
#pragma unroll
        for (int mf = 0; mf < 2; mf++)
#pragma unroll
            for (int kb = 0; kb < 2; kb++)
                a1[mf][kb] = *(const short8*)(hb_in + (size_t)(node0 + row0 + mf * 16 + l15) * 64 + kb * 32 + quad * 8);
#pragma unroll
        for (int nf = 0; nf < 4; nf++)
#pragma unroll
            for (int kb = 0; kb < 2; kb++)
                b1[nf][kb] = *(const short8*)(rootT_b + (size_t)(nf * 16 + l15) * 64 + kb * 32 + quad * 8);
#pragma unroll
        for (int kb = 0; kb < 2; kb++)
#pragma unroll
            for (int mf = 0; mf < 2; mf++)
#pragma unroll
                for (int nf = 0; nf < 4; nf++)
                    acc1[mf][nf] = __builtin_amdgcn_mfma_f32_16x16x32_bf16(a1[mf][kb], b1[nf][kb], acc1[mf][nf], 0, 0, 0);
    }
    // epilogue 1: m = relu(agg/cnt + T + conv_b) -> LDS bf16; zero agg
#pragma unroll
    for (int mf = 0; mf < 2; mf++) {
#pragma unroll
        for (int rr = 0; rr < 4; rr++) {
            int nl = row0 + mf * 16 + quad * 4 + rr;
            float cnt = counts[node0 + nl]; if (cnt < 1.f) cnt = 1.f;
            float rcp = 1.f / cnt;
#pragma unroll
            for (int nf = 0; nf < 4; nf++) {
                int c = nf * 16 + l15;
                float* ap = agg + (size_t)(node0 + nl) * 64 + c;
                float av = *ap;
                *ap = 0.f;
                float mv = av * rcp + acc1[mf][nf][rr] + conv_b[c];
                m_lds[nl * 72 + c] = f2bf(mv > 0.f ? mv : 0.f);
            }
        }
    }
    __syncthreads();

    // ---- stage 2: G = [m|h] @ wcomb^T (32 rows x 256 cols per wave, K=128) ----
    float4v acc2[2][16] = {};
#pragma unroll
    for (int kb = 0; kb < 4; kb++) {
        short8 a2[2];
#pragma unroll
        for (int mf = 0; mf < 2; mf++) {
            if (kb < 2)
                a2[mf] = *(const short8*)(m_lds + (row0 + mf * 16 + l15) * 72 + kb * 32 + quad * 8);
            else
                a2[mf] = *(const short8*)(hb_in + (size_t)(node0 + row0 + mf * 16 + l15) * 64 + (kb - 2) * 32 + quad * 8);
        }
#pragma unroll
        for (int nf = 0; nf < 16; nf++) {
            short8 b = *(const short8*)(wcomb + (size_t)(nf * 16 + l15) * 128 + kb * 32 + quad * 8);
#pragma unroll
            for (int mf = 0; mf < 2; mf++)
                acc2[mf][nf] = __builtin_amdgcn_mfma_f32_16x16x32_bf16(a2[mf], b, acc2[mf][nf], 0, 0, 0);
        }
    }

    // ---- epilogue 2: GRU gates; h update ----
#pragma unroll
    for (int nf0 = 0; nf0 < 4; nf0++) {
        int c = nf0 * 16 + l15;
        float br = bih[c] + bhh[c];
        float bz = bih[64 + c] + bhh[64 + c];
        float bni = bih[128 + c], bnh = bhh[128 + c];
#pragma unroll
        for (int mf = 0; mf < 2; mf++) {
#pragma unroll
            for (int rr = 0; rr < 4; rr++) {
                int node = node0 + row0 + mf * 16 + quad * 4 + rr;
                float gr = 1.f / (1.f + __expf(-(acc2[mf][nf0][rr] + br)));
                float gz = 1.f / (1.f + __expf(-(acc2[mf][nf0 + 4][rr] + bz)));
                float ng = tanhf(acc2[mf][nf0 + 8][rr] + bni + gr * (acc2[mf][nf0 + 12][rr] + bnh));
                float ho = h[(size_t)node * 64 + c];
                float hn = (1.f - gz) * ng + gz * ho;
                h[(size_t)node * 64 + c] = hn;
                hb_out[(size_t)node * 64 + c] = f2bf(hn);
            }
        }
    }
}

// ---- decoder: wave per edge, weights staged in LDS (fp32) ----
__global__ __launch_bounds__(256) void k_decoder(
    const float* __restrict__ h, const int* __restrict__ ei, const float* __restrict__ ea,
    const float* __restrict__ Wd1, const float* __restrict__ bd1,
    const float* __restrict__ Wd2, const float* __restrict__ bd2,
    const float* __restrict__ Wd3, const float* __restrict__ bd3,
    float* __restrict__ out)
{
    __shared__ float w1[64 * 133], w2[32 * 65], w3[4 * 33], b1[64], b2[32], b3[4];
    __shared__ float ein[4][144], d1b[4][64], d2b[4][32];
    int tid = threadIdx.x;
    for (int i = tid; i < 64 * 133; i += 256) w1[i] = Wd1[i];
    for (int i = tid; i < 2048; i += 256) w2[(i >> 6) * 65 + (i & 63)] = Wd2[i];
    if (tid < 128) w3[(tid >> 5) * 33 + (tid & 31)] = Wd3[tid];
    if (tid < 64) b1[tid] = bd1[tid];
    if (tid < 32) b2[tid] = bd2[tid];
    if (tid < 4)  b3[tid] = bd3[tid];
    __syncthreads();
    int wave = tid >> 6, lane = tid & 63;
    for (int it = 0; it < 16; it++) {
        int e = blockIdx.x * 64 + it * 4 + wave;
        int src = ei[e], dst = ei[N_EDGES + e];
        ein[wave][lane]      = h[(size_t)src * 64 + lane];
        ein[wave][64 + lane] = h[(size_t)dst * 64 + lane];
        if (lane < 5) ein[wave][128 + lane] = ea[(size_t)e * 5 + lane];
        __syncthreads();
        {
            float s = b1[lane];
            for (int k = 0; k < 133; k++) s += w1[lane * 133 + k] * ein[wave][k];
            d1b[wave][lane] = s > 0.f ? s : 0.f;
        }
        __syncthreads();
        if (lane < 32) {
            float s = b2[lane];
            for (int k = 0; k < 64; k++) s += w2[lane * 65 + k] * d1b[wave][k];
            d2b[wave][lane] = s > 0.f ? s : 0.f;
        }
        __syncthreads();
        if (lane < 4) {
            float s = b3[lane];
            for (int k = 0; k < 32; k++) s += w3[lane * 33 + k] * d2b[wave][k];
            out[(size_t)e * 4 + lane] = s;
        }
        __syncthreads();
    }
}

extern "C" void kernel_launch(void* const* d_in, const int* in_sizes, int n_in,
                              void* d_out, int out_size, void* d_ws, size_t ws_size,
                              hipStream_t stream)
{
    const float* x      = (const float*)d_in[0];
    const int*   ei     = (const int*)d_in[1];
    const float* ea     = (const float*)d_in[2];
    const float* u      = (const float*)d_in[3];
    const float* Wp     = (const float*)d_in[4];
    const float* bp     = (const float*)d_in[5];
    const float* We1    = (const float*)d_in[6];
    const float* be1    = (const float*)d_in[7];
    const float* We2    = (const float*)d_in[8];
    const float* be2    = (const float*)d_in[9];
    const float* root   = (const float*)d_in[10];
    const float* conv_b = (const float*)d_in[11];
    const float* Wih    = (const float*)d_in[12];
    const float* bih    = (const float*)d_in[13];
    const float* Whh    = (const float*)d_in[14];
    const float* bhh    = (const float*)d_in[15];
    const float* Wd1    = (const float*)d_in[16];
    const float* bd1    = (const float*)d_in[17];
    const float* Wd2    = (const float*)d_in[18];
    const float* bd2    = (const float*)d_in[19];
    const float* Wd3    = (const float*)d_in[20];
    const float* bd3    = (const float*)d_in[21];
    float* out = (float*)d_out;

    char* ws = (char*)d_ws;
    size_t off = 0;
    auto take = [&](size_t bytes) -> char* {
        char* p = ws + off; off = (off + bytes + 255) & ~(size_t)255; return p;
    };
    float*          h      = (float*)take((size_t)N_NODES * 64 * 4);
    unsigned short* hb     = (unsigned short*)take((size_t)N_NODES * 64 * 2);
    unsigned short* hid    = (unsigned short*)take((size_t)N_EDGES * 64 * 2);
    float*          agg    = (float*)take((size_t)N_NODES * 64 * 4);
    float*          cnts   = (float*)take((size_t)N_NODES * 4);
    unsigned short* w2t    = (unsigned short*)take((size_t)64 * KTOT * 2);
    unsigned short* rootTb = (unsigned short*)take((size_t)64 * 64 * 2);
    unsigned short* wcomb  = (unsigned short*)take((size_t)256 * 128 * 2);
    (void)ws_size;

    hipMemsetAsync(cnts, 0, (size_t)N_NODES * 4, stream);
    hipMemsetAsync(agg, 0, (size_t)N_NODES * 64 * 4, stream);
    k_prep<<<144, 256, 0, stream>>>(root, Wih, Whh, rootTb, wcomb);
    k_prep_w2t<<<dim3(17, 64), 256, 0, stream>>>(We2, be2, w2t);
    k_proj<<<8192, 256, 0, stream>>>(x, u, Wp, bp, h, hb);
    k_edge_hidden<<<8192, 256, 0, stream>>>(ea, We1, be1, hid);
    k_counts<<<128, 256, 0, stream>>>(ei, cnts);

    for (int s = 0; s < STEPS; s++) {
        k_msg_fused<<<N_EDGES / 64, 256, 0, stream>>>(hid, hb, w2t, ei, agg);
        k_node<<<N_NODES / 128, 256, 0, stream>>>(hb, rootTb, wcomb, agg, cnts,
                                                  conv_b, bih, bhh, h, hb);
    }
    k_decoder<<<512, 256, 0, stream>>>(h, ei, ea, Wd1, bd1, Wd2, bd2, Wd3, bd3, out);
}

// Round 4
// 381.204 us; speedup vs baseline: 2.4081x; 1.6354x over previous
//
#include <hip/hip_runtime.h>
#include <hip/hip_bf16.h>
#include <stdint.h>

// MPNN latency predictor, MI355X — round 4.
// vs R3: (1) all MFMA B-operand weights stored in FRAG-INTERLEAVED layout so
// every B load is one coalesced 1KB wave transaction (R3's 16-segment gathers
// made msg latency-bound: VALU 8%, MFMA 5%, HBM 1.5%).
// (2) k_msg_fused stages each 8KB kk-block of W2T into LDS once per BLOCK
// (global_load_lds width=16, double-buffered), 4 waves share via ds_read_b128:
// L2 traffic 1.09GB -> 272MB per dispatch. (3) k_node grid 512, coalesced
// wcombf loads.

#define N_NODES 32768
#define N_EDGES 32768
#define STEPS 3

typedef __attribute__((ext_vector_type(8))) short short8;   // 8 bf16 = 4 VGPRs
typedef __attribute__((ext_vector_type(4))) float float4v;  // MFMA C/D

__device__ __forceinline__ float bf2f(unsigned short u) {
    union { unsigned int i; float f; } v; v.i = ((unsigned int)u) << 16; return v.f;
}
__device__ __forceinline__ unsigned short f2bf(float f) {  // RNE
    union { float f; unsigned int i; } v; v.f = f;
    unsigned int x = v.i;
    return (unsigned short)((x + 0x7fffu + ((x >> 16) & 1u)) >> 16);
}
__device__ __forceinline__ unsigned int fbits(float f) {
    union { float f; unsigned int i; } v; v.f = f; return v.i;
}

// pack 8 products hv*hf[j] into a bf16x8 A-frag: round-half-up + v_perm pack
__device__ __forceinline__ short8 packA(float hv, const float* hf) {
    union { short8 v; unsigned int u[4]; } r;
#pragma unroll
    for (int p = 0; p < 4; p++) {
        unsigned int p0 = fbits(hv * hf[2 * p]) + 0x8000u;
        unsigned int p1 = fbits(hv * hf[2 * p + 1]) + 0x8000u;
        r.u[p] = __builtin_amdgcn_perm(p1, p0, 0x07060302u);  // {hi16(p0), hi16(p1)}
    }
    return r.v;
}

// async global->LDS, 16B/lane; lds dest = wave-uniform base + lane*16
__device__ __forceinline__ void gload_lds16(const void* g, void* l) {
    __builtin_amdgcn_global_load_lds(
        (__attribute__((address_space(1))) void*)g,
        (__attribute__((address_space(3))) void*)l, 16, 0, 0);
}

// ===================== prep kernels (frag-interleaved layouts) ==============
// Frag element convention for a B-operand tile row-block of 16 (o = blk*16 +
// (lane&15)) and k-window of 32 (k = kwin*32 + (lane>>4)*8 + j):
//   elem index = (chunk*64 + lane)*8 + j, chunk enumerates (kwin, blk).

// rootTf: 4096 elems; chunks g=kb*4+nf (kb<2,nf<4): val = root[k*64+o]
// wcombf: 32768 elems; chunks g=kb*16+nf (kb<4,nf<16): rows cp = nf*16+l15:
//   [0,128): [Wih|Whh] (r,z); [128,192): [Wih_n|0]; [192,256): [0|Whh_n]
__global__ __launch_bounds__(256) void k_prep(
    const float* __restrict__ root, const float* __restrict__ Wih,
    const float* __restrict__ Whh,
    unsigned short* __restrict__ rootTf, unsigned short* __restrict__ wcombf)
{
    int i = blockIdx.x * 256 + threadIdx.x;
    if (i < 4096) {
        int j = i & 7, lane = (i >> 3) & 63, g = i >> 9;   // g<8
        int kb = g >> 2, nf = g & 3;
        int o = nf * 16 + (lane & 15);
        int k = kb * 32 + (lane >> 4) * 8 + j;
        rootTf[i] = f2bf(root[k * 64 + o]);
    } else if (i < 4096 + 32768) {
        int t = i - 4096;
        int j = t & 7, lane = (t >> 3) & 63, g = t >> 9;   // g<64
        int kb = g >> 4, nf = g & 15;
        int cp = nf * 16 + (lane & 15);
        int k = kb * 32 + (lane >> 4) * 8 + j;
        float v;
        if (cp < 128)      v = (k < 64) ? Wih[cp * 64 + k] : Whh[cp * 64 + (k - 64)];
        else if (cp < 192) v = (k < 64) ? Wih[cp * 64 + k] : 0.f;
        else               v = (k < 64) ? 0.f : Whh[(cp - 64) * 64 + (k - 64)];
        wcombf[t] = f2bf(v);
    }
}

// w2tf: 65 kk-blocks of 4096 elems. chunk g=half*4+nf (half<2,nf<4):
//   o = nf*16+(lane&15), hh = half*32+(lane>>4)*8+j
//   kk<64: We2[(hh*64+o)*64+kk]; kk==64 (bias fold): be2[hh*64+o]
__global__ __launch_bounds__(256) void k_prep_w2t(
    const float* __restrict__ We2, const float* __restrict__ be2,
    unsigned short* __restrict__ w2tf)
{
    int t = blockIdx.x * 256 + threadIdx.x;   // t < 65*4096 = 266240
    if (t >= 65 * 4096) return;
    int kk = t >> 12, r = t & 4095;
    int j = r & 7, lane = (r >> 3) & 63, g = r >> 9;  // g<8
    int half = g >> 2, nf = g & 3;
    int o = nf * 16 + (lane & 15);
    int hh = half * 32 + (lane >> 4) * 8 + j;
    float v = (kk < 64) ? We2[((size_t)(hh * 64 + o)) * 64 + kk]
                        : be2[(size_t)hh * 64 + o];
    w2tf[t] = f2bf(v);
}

// ---- node input projection: h = tanh([x,u] @ Wp^T + bp) ----
__global__ __launch_bounds__(256) void k_proj(
    const float* __restrict__ x, const float* __restrict__ u,
    const float* __restrict__ Wp, const float* __restrict__ bp,
    float* __restrict__ h, unsigned short* __restrict__ hb)
{
    int idx = blockIdx.x * 256 + threadIdx.x;
    int n = idx >> 6, j = idx & 63;
    const float* wr = Wp + j * 23;
    const float* xr = x + (size_t)n * 12;
    float s = bp[j];
#pragma unroll
    for (int i = 0; i < 12; i++) s += xr[i] * wr[i];
#pragma unroll
    for (int i = 0; i < 11; i++) s += u[i] * wr[12 + i];
    float v = tanhf(s);
    h[idx] = v; hb[idx] = f2bf(v);
}

// ---- edge hidden (row-major, stride 64): hid = relu(ea @ We1^T + be1) ----
__global__ __launch_bounds__(256) void k_edge_hidden(
    const float* __restrict__ ea, const float* __restrict__ We1,
    const float* __restrict__ be1, unsigned short* __restrict__ hidb)
{
    int idx = blockIdx.x * 256 + threadIdx.x;
    int e = idx >> 6, j = idx & 63;
    float s = be1[j];
#pragma unroll
    for (int i = 0; i < 5; i++) s += ea[(size_t)e * 5 + i] * We1[j * 5 + i];
    hidb[idx] = f2bf(s > 0.f ? s : 0.f);
}

__global__ __launch_bounds__(256) void k_counts(
    const int* __restrict__ ei, float* __restrict__ counts)
{
    int i = blockIdx.x * 256 + threadIdx.x;
    if (i < N_EDGES) atomicAdd(&counts[ei[N_EDGES + i]], 1.0f);
}

// ===================== fused msg GEMM ======================================
// msg[e,o] = sum_{kk<65,hh<64} A * W2T, A = hid[e,kk]*h[src,hh] (kk=64: hid=1,
// pairs h with be2 rows — the ew-bias contribution).
// Block = 4 waves x 16 edges. Per kk: 8KB B-block staged in LDS (double-buf,
// global_load_lds w=16), shared by all 4 waves. atomicAdd scatter epilogue.
__global__ __launch_bounds__(256) void k_msg_fused(
    const unsigned short* __restrict__ hid,   // (E,64) bf16
    const unsigned short* __restrict__ hb,    // (N,64) bf16
    const unsigned short* __restrict__ w2tf,  // (65*4096) frag-interleaved
    const int* __restrict__ ei,
    float* __restrict__ agg)
{
    __shared__ unsigned short buf[2][4096];   // 8KB x2
    int tid = threadIdx.x, wave = tid >> 6, lane = tid & 63;
    int l15 = lane & 15, quad = lane >> 4;
    int ebase = blockIdx.x * 64 + wave * 16;
    int e_a = ebase + l15;
    int src = ei[e_a];

    // hid row of this lane's edge: 64 bf16 in registers
    union { short8 v[8]; unsigned short u[64]; } hrow;
#pragma unroll
    for (int i = 0; i < 8; i++)
        hrow.v[i] = *(const short8*)(hid + (size_t)e_a * 64 + i * 8);

    // h[src] windows (f32): half0 -> hh=quad*8+j, half1 -> hh=32+quad*8+j
    float hf0[8], hf1[8];
    {
        short8 h0 = *(const short8*)(hb + (size_t)src * 64 + quad * 8);
        short8 h1 = *(const short8*)(hb + (size_t)src * 64 + 32 + quad * 8);
#pragma unroll
        for (int j = 0; j < 8; j++) {
            hf0[j] = bf2f((unsigned short)h0[j]);
            hf1[j] = bf2f((unsigned short)h1[j]);
        }
    }

    // prefetch kk=0: each wave stages 2 x 1KB chunks (chunk c = wave*2 + i)
    {
        int c0 = wave * 2, c1 = wave * 2 + 1;
        gload_lds16(w2tf + (size_t)c0 * 512 + lane * 8, &buf[0][c0 * 512]);
        gload_lds16(w2tf + (size_t)c1 * 512 + lane * 8, &buf[0][c1 * 512]);
    }

    float4v acc[4] = {};
    int cur = 0;
#pragma unroll
    for (int kk = 0; kk < 65; kk++) {
        __syncthreads();   // buf[cur] staged (vmcnt drain) + prev reads done
        if (kk < 64) {     // prefetch kk+1 into the other buffer
            const unsigned short* g = w2tf + (size_t)(kk + 1) * 4096;
            int c0 = wave * 2, c1 = wave * 2 + 1;
            gload_lds16(g + (size_t)c0 * 512 + lane * 8, &buf[cur ^ 1][c0 * 512]);
            gload_lds16(g + (size_t)c1 * 512 + lane * 8, &buf[cur ^ 1][c1 * 512]);
        }
        float hv = (kk < 64) ? bf2f(hrow.u[kk]) : 1.0f;
        short8 a0 = packA(hv, hf0);
        short8 a1 = packA(hv, hf1);
        const unsigned short* bp = &buf[cur][0];
#pragma unroll
        for (int nf = 0; nf < 4; nf++) {
            short8 b0 = *(const short8*)(bp + (0 * 4 + nf) * 512 + lane * 8);
            acc[nf] = __builtin_amdgcn_mfma_f32_16x16x32_bf16(a0, b0, acc[nf], 0, 0, 0);
        }
#pragma unroll
        for (int nf = 0; nf < 4; nf++) {
            short8 b1 = *(const short8*)(bp + (1 * 4 + nf) * 512 + lane * 8);
            acc[nf] = __builtin_amdgcn_mfma_f32_16x16x32_bf16(a1, b1, acc[nf], 0, 0, 0);
        }
        cur ^= 1;
    }

    // epilogue: C row = quad*4+r (edge), col = nf*16+l15; scatter-add to dst
    int dsts[4];
#pragma unroll
    for (int r = 0; r < 4; r++) dsts[r] = ei[N_EDGES + ebase + quad * 4 + r];
#pragma unroll
    for (int nf = 0; nf < 4; nf++)
#pragma unroll
        for (int r = 0; r < 4; r++)
            atomicAdd(agg + (size_t)dsts[r] * 64 + nf * 16 + l15, acc[nf][r]);
}

// ===================== fused node update ===================================
// T=h@rootT^T -> m=relu(agg/cnt+T+conv_b) (LDS) -> G=[m|h]@wcomb^T -> GRU.
// Grid 512 (64 nodes/block, wave=16 nodes). Zeroes agg for next step.
__global__ __launch_bounds__(256) void k_node(
    const unsigned short* __restrict__ hb_in,
    const unsigned short* __restrict__ rootTf,
    const unsigned short* __restrict__ wcombf,
    float* __restrict__ agg, const float* __restrict__ counts,
    const float* __restrict__ conv_b,
    const float* __restrict__ bih, const float* __restrict__ bhh,
    float* __restrict__ h, unsigned short* __restrict__ hb_out)
{
    __shared__ unsigned short m_lds[64 * 72];  // stride 72: 2-way banks (free)
    int tid = threadIdx.x, w = tid >> 6, lane = tid & 63;
    int l15 = lane & 15, quad = lane >> 4;
    int node0 = blockIdx.x * 64;
    int row0 = w * 16;

    // ---- stage 1: T = h_tile @ rootT^T (16 rows x 64 cols per wave) ----
    float4v acc1[4] = {};
    {
        short8 a1[2];
#pragma unroll
        for (int kb = 0; kb < 2; kb++)
            a1[kb] = *(const short8*)(hb_in + (size_t)(node0 + row0 + l15) * 64 + kb * 32 + quad * 8);
#pragma unroll
        for (int kb = 0; kb < 2; kb++)
#pragma unroll
            for (int nf = 0; nf < 4; nf++) {
                short8 b = *(const short8*)(rootTf + (size_t)((kb * 4 + nf) * 64 + lane) * 8);
                acc1[nf] = __builtin_amdgcn_mfma_f32_16x16x32_bf16(a1[kb], b, acc1[nf], 0, 0, 0);
            }
    }
    // epilogue 1: m = relu(agg/cnt + T + conv_b) -> LDS bf16; zero agg
#pragma unroll
    for (int rr = 0; rr < 4; rr++) {
        int nl = row0 + quad * 4 + rr;
        float cnt = counts[node0 + nl]; if (cnt < 1.f) cnt = 1.f;
        float rcp = 1.f / cnt;
#pragma unroll
        for (int nf = 0; nf < 4; nf++) {
            int c = nf * 16 + l15;
            float* ap = agg + (size_t)(node0 + nl) * 64 + c;
            float av = *ap;
            *ap = 0.f;
            float mv = av * rcp + acc1[nf][rr] + conv_b[c];
            m_lds[nl * 72 + c] = f2bf(mv > 0.f ? mv : 0.f);
        }
    }
    __syncthreads();

    // ---- stage 2: G = [m|h] @ wcomb^T (16 rows x 256 cols, K=128) ----
    float4v acc2[16] = {};
#pragma unroll
    for (int kb = 0; kb < 4; kb++) {
        short8 a2;
        if (kb < 2)
            a2 = *(const short8*)(m_lds + (row0 + l15) * 72 + kb * 32 + quad * 8);
        else
            a2 = *(const short8*)(hb_in + (size_t)(node0 + row0 + l15) * 64 + (kb - 2) * 32 + quad * 8);
#pragma unroll
        for (int nf = 0; nf < 16; nf++) {
            short8 b = *(const short8*)(wcombf + (size_t)((kb * 16 + nf) * 64 + lane) * 8);
            acc2[nf] = __builtin_amdgcn_mfma_f32_16x16x32_bf16(a2, b, acc2[nf], 0, 0, 0);
        }
    }

    // ---- epilogue 2: GRU gates; h update ----
#pragma unroll
    for (int nf0 = 0; nf0 < 4; nf0++) {
        int c = nf0 * 16 + l15;
        float br = bih[c] + bhh[c];
        float bz = bih[64 + c] + bhh[64 + c];
        float bni = bih[128 + c], bnh = bhh[128 + c];
#pragma unroll
        for (int rr = 0; rr < 4; rr++) {
            int node = node0 + row0 + quad * 4 + rr;
            float gr = 1.f / (1.f + __expf(-(acc2[nf0][rr] + br)));
            float gz = 1.f / (1.f + __expf(-(acc2[nf0 + 4][rr] + bz)));
            float ng = tanhf(acc2[nf0 + 8][rr] + bni + gr * (acc2[nf0 + 12][rr] + bnh));
            float ho = h[(size_t)node * 64 + c];
            float hn = (1.f - gz) * ng + gz * ho;
            h[(size_t)node * 64 + c] = hn;
            hb_out[(size_t)node * 64 + c] = f2bf(hn);
        }
    }
}

// ---- decoder: wave per edge, weights staged in LDS (fp32) ----
__global__ __launch_bounds__(256) void k_decoder(
    const float* __restrict__ h, const int* __restrict__ ei, const float* __restrict__ ea,
    const float* __restrict__ Wd1, const float* __restrict__ bd1,
    const float* __restrict__ Wd2, const float* __restrict__ bd2,
    const float* __restrict__ Wd3, const float* __restrict__ bd3,
    float* __restrict__ out)
{
    __shared__ float w1[64 * 133], w2[32 * 65], w3[4 * 33], b1[64], b2[32], b3[4];
    __shared__ float ein[4][144], d1b[4][64], d2b[4][32];
    int tid = threadIdx.x;
    for (int i = tid; i < 64 * 133; i += 256) w1[i] = Wd1[i];
    for (int i = tid; i < 2048; i += 256) w2[(i >> 6) * 65 + (i & 63)] = Wd2[i];
    if (tid < 128) w3[(tid >> 5) * 33 + (tid & 31)] = Wd3[tid];
    if (tid < 64) b1[tid] = bd1[tid];
    if (tid < 32) b2[tid] = bd2[tid];
    if (tid < 4)  b3[tid] = bd3[tid];
    __syncthreads();
    int wave = tid >> 6, lane = tid & 63;
    for (int it = 0; it < 16; it++) {
        int e = blockIdx.x * 64 + it * 4 + wave;
        int src = ei[e], dst = ei[N_EDGES + e];
        ein[wave][lane]      = h[(size_t)src * 64 + lane];
        ein[wave][64 + lane] = h[(size_t)dst * 64 + lane];
        if (lane < 5) ein[wave][128 + lane] = ea[(size_t)e * 5 + lane];
        __syncthreads();
        {
            float s = b1[lane];
            for (int k = 0; k < 133; k++) s += w1[lane * 133 + k] * ein[wave][k];
            d1b[wave][lane] = s > 0.f ? s : 0.f;
        }
        __syncthreads();
        if (lane < 32) {
            float s = b2[lane];
            for (int k = 0; k < 64; k++) s += w2[lane * 65 + k] * d1b[wave][k];
            d2b[wave][lane] = s > 0.f ? s : 0.f;
        }
        __syncthreads();
        if (lane < 4) {
            float s = b3[lane];
            for (int k = 0; k < 32; k++) s += w3[lane * 33 + k] * d2b[wave][k];
            out[(size_t)e * 4 + lane] = s;
        }
        __syncthreads();
    }
}

extern "C" void kernel_launch(void* const* d_in, const int* in_sizes, int n_in,
                              void* d_out, int out_size, void* d_ws, size_t ws_size,
                              hipStream_t stream)
{
    const float* x      = (const float*)d_in[0];
    const int*   ei     = (const int*)d_in[1];
    const float* ea     = (const float*)d_in[2];
    const float* u      = (const float*)d_in[3];
    const float* Wp     = (const float*)d_in[4];
    const float* bp     = (const float*)d_in[5];
    const float* We1    = (const float*)d_in[6];
    const float* be1    = (const float*)d_in[7];
    const float* We2    = (const float*)d_in[8];
    const float* be2    = (const float*)d_in[9];
    const float* root   = (const float*)d_in[10];
    const float* conv_b = (const float*)d_in[11];
    const float* Wih    = (const float*)d_in[12];
    const float* bih    = (const float*)d_in[13];
    const float* Whh    = (const float*)d_in[14];
    const float* bhh    = (const float*)d_in[15];
    const float* Wd1    = (const float*)d_in[16];
    const float* bd1    = (const float*)d_in[17];
    const float* Wd2    = (const float*)d_in[18];
    const float* bd2    = (const float*)d_in[19];
    const float* Wd3    = (const float*)d_in[20];
    const float* bd3    = (const float*)d_in[21];
    float* out = (float*)d_out;

    char* ws = (char*)d_ws;
    size_t off = 0;
    auto take = [&](size_t bytes) -> char* {
        char* p = ws + off; off = (off + bytes + 255) & ~(size_t)255; return p;
    };
    float*          h      = (float*)take((size_t)N_NODES * 64 * 4);
    unsigned short* hb     = (unsigned short*)take((size_t)N_NODES * 64 * 2);
    unsigned short* hid    = (unsigned short*)take((size_t)N_EDGES * 64 * 2);
    float*          agg    = (float*)take((size_t)N_NODES * 64 * 4);
    float*          cnts   = (float*)take((size_t)N_NODES * 4);
    unsigned short* w2tf   = (unsigned short*)take((size_t)65 * 4096 * 2);
    unsigned short* rootTf = (unsigned short*)take((size_t)4096 * 2);
    unsigned short* wcombf = (unsigned short*)take((size_t)32768 * 2);
    (void)ws_size;

    hipMemsetAsync(cnts, 0, (size_t)N_NODES * 4, stream);
    hipMemsetAsync(agg, 0, (size_t)N_NODES * 64 * 4, stream);
    k_prep<<<144, 256, 0, stream>>>(root, Wih, Whh, rootTf, wcombf);
    k_prep_w2t<<<1040, 256, 0, stream>>>(We2, be2, w2tf);
    k_proj<<<8192, 256, 0, stream>>>(x, u, Wp, bp, h, hb);
    k_edge_hidden<<<8192, 256, 0, stream>>>(ea, We1, be1, hid);
    k_counts<<<128, 256, 0, stream>>>(ei, cnts);

    for (int s = 0; s < STEPS; s++) {
        k_msg_fused<<<N_EDGES / 64, 256, 0, stream>>>(hid, hb, w2tf, ei, agg);
        k_node<<<N_NODES / 64, 256, 0, stream>>>(hb, rootTf, wcombf, agg, cnts,
                                                 conv_b, bih, bhh, h, hb);
    }
    k_decoder<<<512, 256, 0, stream>>>(h, ei, ea, Wd1, bd1, Wd2, bd2, Wd3, bd3, out);
}

// Round 5
// 333.942 us; speedup vs baseline: 2.7489x; 1.1415x over previous
//
#include <hip/hip_runtime.h>
#include <hip/hip_bf16.h>
#include <stdint.h>

// MPNN latency predictor, MI355X — round 5.
// vs R4: (1) k_decoder rewritten as 3-stage MFMA pipeline (layer1 K=160 with
// bias fold, d1 through LDS in A-frag order, layer2 MFMA, layer3 scalar) —
// was 64us of serial scalar MACs at MfmaUtil=0. (2) k_msg_fused: K split
// across wave pairs (kh0: kk 0..31, kh1: kk 32..64), two LDS staging regions,
// grid 1024 -> 4-5 blocks/CU (was 2) to hide the per-kk barrier drain.

#define N_NODES 32768
#define N_EDGES 32768
#define STEPS 3

typedef __attribute__((ext_vector_type(8))) short short8;   // 8 bf16 = 4 VGPRs
typedef __attribute__((ext_vector_type(4))) float float4v;  // MFMA C/D

__device__ __forceinline__ float bf2f(unsigned short u) {
    union { unsigned int i; float f; } v; v.i = ((unsigned int)u) << 16; return v.f;
}
__device__ __forceinline__ unsigned short f2bf(float f) {  // RNE
    union { float f; unsigned int i; } v; v.f = f;
    unsigned int x = v.i;
    return (unsigned short)((x + 0x7fffu + ((x >> 16) & 1u)) >> 16);
}
__device__ __forceinline__ unsigned int fbits(float f) {
    union { float f; unsigned int i; } v; v.f = f; return v.i;
}

// pack 8 products hv*hf[j] into a bf16x8 A-frag: round-half-up + v_perm pack
__device__ __forceinline__ short8 packA(float hv, const float* hf) {
    union { short8 v; unsigned int u[4]; } r;
#pragma unroll
    for (int p = 0; p < 4; p++) {
        unsigned int p0 = fbits(hv * hf[2 * p]) + 0x8000u;
        unsigned int p1 = fbits(hv * hf[2 * p + 1]) + 0x8000u;
        r.u[p] = __builtin_amdgcn_perm(p1, p0, 0x07060302u);  // {hi16(p0), hi16(p1)}
    }
    return r.v;
}

// async global->LDS, 16B/lane; lds dest = wave-uniform base + lane*16
__device__ __forceinline__ void gload_lds16(const void* g, void* l) {
    __builtin_amdgcn_global_load_lds(
        (__attribute__((address_space(1))) void*)g,
        (__attribute__((address_space(3))) void*)l, 16, 0, 0);
}

// ===================== prep kernels (frag-interleaved layouts) ==============
// Frag convention: B-tile rows o = nf*16 + (lane&15), k = kb*32 + (lane>>4)*8
// + j; element index = (chunk*64 + lane)*8 + j.

__global__ __launch_bounds__(256) void k_prep(
    const float* __restrict__ root, const float* __restrict__ Wih,
    const float* __restrict__ Whh,
    unsigned short* __restrict__ rootTf, unsigned short* __restrict__ wcombf)
{
    int i = blockIdx.x * 256 + threadIdx.x;
    if (i < 4096) {
        int j = i & 7, lane = (i >> 3) & 63, g = i >> 9;   // g<8
        int kb = g >> 2, nf = g & 3;
        int o = nf * 16 + (lane & 15);
        int k = kb * 32 + (lane >> 4) * 8 + j;
        rootTf[i] = f2bf(root[k * 64 + o]);
    } else if (i < 4096 + 32768) {
        int t = i - 4096;
        int j = t & 7, lane = (t >> 3) & 63, g = t >> 9;   // g<64
        int kb = g >> 4, nf = g & 15;
        int cp = nf * 16 + (lane & 15);
        int k = kb * 32 + (lane >> 4) * 8 + j;
        float v;
        if (cp < 128)      v = (k < 64) ? Wih[cp * 64 + k] : Whh[cp * 64 + (k - 64)];
        else if (cp < 192) v = (k < 64) ? Wih[cp * 64 + k] : 0.f;
        else               v = (k < 64) ? 0.f : Whh[(cp - 64) * 64 + (k - 64)];
        wcombf[t] = f2bf(v);
    }
}

// w2tf: 65 kk-blocks of 4096. chunk g=half*4+nf: o=nf*16+l15, hh=half*32+q*8+j
__global__ __launch_bounds__(256) void k_prep_w2t(
    const float* __restrict__ We2, const float* __restrict__ be2,
    unsigned short* __restrict__ w2tf)
{
    int t = blockIdx.x * 256 + threadIdx.x;   // t < 65*4096 = 266240
    if (t >= 65 * 4096) return;
    int kk = t >> 12, r = t & 4095;
    int j = r & 7, lane = (r >> 3) & 63, g = r >> 9;  // g<8
    int half = g >> 2, nf = g & 3;
    int o = nf * 16 + (lane & 15);
    int hh = half * 32 + (lane >> 4) * 8 + j;
    float v = (kk < 64) ? We2[((size_t)(hh * 64 + o)) * 64 + kk]
                        : be2[(size_t)hh * 64 + o];
    w2tf[t] = f2bf(v);
}

// decoder weights: wd1f (20 chunks, K=160 incl bias@133), wd2f (4 chunks)
__global__ __launch_bounds__(256) void k_prep_dec(
    const float* __restrict__ Wd1, const float* __restrict__ bd1,
    const float* __restrict__ Wd2,
    unsigned short* __restrict__ wd1f, unsigned short* __restrict__ wd2f)
{
    int i = blockIdx.x * 256 + threadIdx.x;
    if (i < 10240) {
        int j = i & 7, lane = (i >> 3) & 63, g = i >> 9;  // g<20
        int kb = g >> 2, nf = g & 3;
        int o = nf * 16 + (lane & 15);
        int k = kb * 32 + (lane >> 4) * 8 + j;
        float v = (k < 133) ? Wd1[(size_t)o * 133 + k] : (k == 133 ? bd1[o] : 0.f);
        wd1f[i] = f2bf(v);
    } else if (i < 10240 + 2048) {
        int t = i - 10240;
        int j = t & 7, lane = (t >> 3) & 63, g = t >> 9;  // g<4
        int kb = g >> 1, nf = g & 1;
        int o = nf * 16 + (lane & 15);
        int k = kb * 32 + (lane >> 4) * 8 + j;
        wd2f[t] = f2bf(Wd2[(size_t)o * 64 + k]);
    }
}

// ---- node input projection: h = tanh([x,u] @ Wp^T + bp) ----
__global__ __launch_bounds__(256) void k_proj(
    const float* __restrict__ x, const float* __restrict__ u,
    const float* __restrict__ Wp, const float* __restrict__ bp,
    float* __restrict__ h, unsigned short* __restrict__ hb)
{
    int idx = blockIdx.x * 256 + threadIdx.x;
    int n = idx >> 6, j = idx & 63;
    const float* wr = Wp + j * 23;
    const float* xr = x + (size_t)n * 12;
    float s = bp[j];
#pragma unroll
    for (int i = 0; i < 12; i++) s += xr[i] * wr[i];
#pragma unroll
    for (int i = 0; i < 11; i++) s += u[i] * wr[12 + i];
    float v = tanhf(s);
    h[idx] = v; hb[idx] = f2bf(v);
}

// ---- edge hidden: hid = relu(ea @ We1^T + be1) ----
__global__ __launch_bounds__(256) void k_edge_hidden(
    const float* __restrict__ ea, const float* __restrict__ We1,
    const float* __restrict__ be1, unsigned short* __restrict__ hidb)
{
    int idx = blockIdx.x * 256 + threadIdx.x;
    int e = idx >> 6, j = idx & 63;
    float s = be1[j];
#pragma unroll
    for (int i = 0; i < 5; i++) s += ea[(size_t)e * 5 + i] * We1[j * 5 + i];
    hidb[idx] = f2bf(s > 0.f ? s : 0.f);
}

__global__ __launch_bounds__(256) void k_counts(
    const int* __restrict__ ei, float* __restrict__ counts)
{
    int i = blockIdx.x * 256 + threadIdx.x;
    if (i < N_EDGES) atomicAdd(&counts[ei[N_EDGES + i]], 1.0f);
}

// ===================== fused msg GEMM (K-split) ============================
// Block = 4 waves: wave = (kh<<1)|mf. mf picks 16-edge group (32 edges/block),
// kh picks K-half (kh0: kk 0..31, kh1: kk 32..64 incl bias row). Each kh has
// its own double-buffered 8KB LDS staging region; partial sums merge via
// atomicAdd. Grid 1024 -> 4-5 blocks/CU.
__global__ __launch_bounds__(256) void k_msg_fused(
    const unsigned short* __restrict__ hid,   // (E,64) bf16
    const unsigned short* __restrict__ hb,    // (N,64) bf16
    const unsigned short* __restrict__ w2tf,  // (65*4096) frag-interleaved
    const int* __restrict__ ei,
    float* __restrict__ agg)
{
    __shared__ unsigned short buf[2][2][4096];   // [kh][dbuf] 8KB each = 32KB
    int tid = threadIdx.x, wave = tid >> 6, lane = tid & 63;
    int l15 = lane & 15, quad = lane >> 4;
    int mf = wave & 1, kh = wave >> 1;
    int ebase = blockIdx.x * 32 + mf * 16;
    int e_a = ebase + l15;
    int src = ei[e_a];

    union { short8 v[8]; unsigned short u[64]; } hrow;
#pragma unroll
    for (int i = 0; i < 8; i++)
        hrow.v[i] = *(const short8*)(hid + (size_t)e_a * 64 + i * 8);

    float hf0[8], hf1[8];
    {
        short8 h0 = *(const short8*)(hb + (size_t)src * 64 + quad * 8);
        short8 h1 = *(const short8*)(hb + (size_t)src * 64 + 32 + quad * 8);
#pragma unroll
        for (int j = 0; j < 8; j++) {
            hf0[j] = bf2f((unsigned short)h0[j]);
            hf1[j] = bf2f((unsigned short)h1[j]);
        }
    }

    // stage kk-block kkv into buf[kh][db]; wave mf stages chunks mf*4..mf*4+3
    auto stage = [&](int kkv, int db) {
        const unsigned short* g = w2tf + (size_t)kkv * 4096;
#pragma unroll
        for (int c = 0; c < 4; c++) {
            int chunk = mf * 4 + c;
            gload_lds16(g + (size_t)chunk * 512 + lane * 8, &buf[kh][db][chunk * 512]);
        }
    };

    int kk0 = kh ? 32 : 0;
    stage(kk0, 0);

    float4v acc[4] = {};
    int cur = 0;
#pragma unroll
    for (int i = 0; i <= 32; i++) {
        __syncthreads();   // staging of buf[*][cur] complete; prev reads done
        // prefetch next kk for this kh (kh0 has 32 iters, kh1 has 33)
        if ((kh == 0 && i + 1 < 32) || (kh == 1 && i + 1 <= 32))
            stage(kk0 + i + 1, cur ^ 1);
        bool active = (kh == 1) || (i < 32);
        if (active) {
            float hva = bf2f(hrow.u[i & 31]);                       // kh0: kk=i
            float hvb = (i == 32) ? 1.0f : bf2f(hrow.u[32 + (i & 31)]);  // kh1
            float hv = kh ? hvb : hva;
            short8 a0 = packA(hv, hf0);
            short8 a1 = packA(hv, hf1);
            const unsigned short* bp = &buf[kh][cur][0];
#pragma unroll
            for (int nf = 0; nf < 4; nf++) {
                short8 b0 = *(const short8*)(bp + (0 * 4 + nf) * 512 + lane * 8);
                acc[nf] = __builtin_amdgcn_mfma_f32_16x16x32_bf16(a0, b0, acc[nf], 0, 0, 0);
            }
#pragma unroll
            for (int nf = 0; nf < 4; nf++) {
                short8 b1 = *(const short8*)(bp + (1 * 4 + nf) * 512 + lane * 8);
                acc[nf] = __builtin_amdgcn_mfma_f32_16x16x32_bf16(a1, b1, acc[nf], 0, 0, 0);
            }
        }
        cur ^= 1;
    }

    int dsts[4];
#pragma unroll
    for (int r = 0; r < 4; r++) dsts[r] = ei[N_EDGES + ebase + quad * 4 + r];
#pragma unroll
    for (int nf = 0; nf < 4; nf++)
#pragma unroll
        for (int r = 0; r < 4; r++)
            atomicAdd(agg + (size_t)dsts[r] * 64 + nf * 16 + l15, acc[nf][r]);
}

// ===================== fused node update ===================================
__global__ __launch_bounds__(256) void k_node(
    const unsigned short* __restrict__ hb_in,
    const unsigned short* __restrict__ rootTf,
    const unsigned short* __restrict__ wcombf,
    float* __restrict__ agg, const float* __restrict__ counts,
    const float* __restrict__ conv_b,
    const float* __restrict__ bih, const float* __restrict__ bhh,
    float* __restrict__ h, unsigned short* __restrict__ hb_out)
{
    __shared__ unsigned short m_lds[64 * 72];
    int tid = threadIdx.x, w = tid >> 6, lane = tid & 63;
    int l15 = lane & 15, quad = lane >> 4;
    int node0 = blockIdx.x * 64;
    int row0 = w * 16;

    float4v acc1[4] = {};
    {
        short8 a1[2];
#pragma unroll
        for (int kb = 0; kb < 2; kb++)
            a1[kb] = *(const short8*)(hb_in + (size_t)(node0 + row0 + l15) * 64 + kb * 32 + quad * 8);
#pragma unroll
        for (int kb = 0; kb < 2; kb++)
#pragma unroll
            for (int nf = 0; nf < 4; nf++) {
                short8 b = *(const short8*)(rootTf + (size_t)((kb * 4 + nf) * 64 + lane) * 8);
                acc1[nf] = __builtin_amdgcn_mfma_f32_16x16x32_bf16(a1[kb], b, acc1[nf], 0, 0, 0);
            }
    }
#pragma unroll
    for (int rr = 0; rr < 4; rr++) {
        int nl = row0 + quad * 4 + rr;
        float cnt = counts[node0 + nl]; if (cnt < 1.f) cnt = 1.f;
        float rcp = 1.f / cnt;
#pragma unroll
        for (int nf = 0; nf < 4; nf++) {
            int c = nf * 16 + l15;
            float* ap = agg + (size_t)(node0 + nl) * 64 + c;
            float av = *ap;
            *ap = 0.f;
            float mv = av * rcp + acc1[nf][rr] + conv_b[c];
            m_lds[nl * 72 + c] = f2bf(mv > 0.f ? mv : 0.f);
        }
    }
    __syncthreads();

    float4v acc2[16] = {};
#pragma unroll
    for (int kb = 0; kb < 4; kb++) {
        short8 a2;
        if (kb < 2)
            a2 = *(const short8*)(m_lds + (row0 + l15) * 72 + kb * 32 + quad * 8);
        else
            a2 = *(const short8*)(hb_in + (size_t)(node0 + row0 + l15) * 64 + (kb - 2) * 32 + quad * 8);
#pragma unroll
        for (int nf = 0; nf < 16; nf++) {
            short8 b = *(const short8*)(wcombf + (size_t)((kb * 16 + nf) * 64 + lane) * 8);
            acc2[nf] = __builtin_amdgcn_mfma_f32_16x16x32_bf16(a2, b, acc2[nf], 0, 0, 0);
        }
    }

#pragma unroll
    for (int nf0 = 0; nf0 < 4; nf0++) {
        int c = nf0 * 16 + l15;
        float br = bih[c] + bhh[c];
        float bz = bih[64 + c] + bhh[64 + c];
        float bni = bih[128 + c], bnh = bhh[128 + c];
#pragma unroll
        for (int rr = 0; rr < 4; rr++) {
            int node = node0 + row0 + quad * 4 + rr;
            float gr = 1.f / (1.f + __expf(-(acc2[nf0][rr] + br)));
            float gz = 1.f / (1.f + __expf(-(acc2[nf0 + 4][rr] + bz)));
            float ng = tanhf(acc2[nf0 + 8][rr] + bni + gr * (acc2[nf0 + 12][rr] + bnh));
            float ho = h[(size_t)node * 64 + c];
            float hn = (1.f - gz) * ng + gz * ho;
            h[(size_t)node * 64 + c] = hn;
            hb_out[(size_t)node * 64 + c] = f2bf(hn);
        }
    }
}

// ===================== MFMA decoder ========================================
// Wave = 16 edges, fully intra-wave (no __syncthreads).
// L1: [hb_src|hb_dst|ea,1,0pad] (K=160) @ wd1f -> d1 (relu) -> LDS A-frag order
// L2: d1 @ wd2f (K=64,N=32) + bd2, relu -> LDS [16][33] f32
// L3: scalar, one (edge,t) per lane.
__global__ __launch_bounds__(256) void k_decoder(
    const unsigned short* __restrict__ hb, const int* __restrict__ ei,
    const float* __restrict__ ea,
    const unsigned short* __restrict__ wd1f, const unsigned short* __restrict__ wd2f,
    const float* __restrict__ bd2,
    const float* __restrict__ Wd3, const float* __restrict__ bd3,
    float* __restrict__ out)
{
    __shared__ unsigned short d1f[4][1024];  // per-wave: 2 frags x 512
    __shared__ float d2s[4][16 * 33];        // per-wave: 16 edges x 32 (+pad)
    int tid = threadIdx.x, w = tid >> 6, lane = tid & 63;
    int l15 = lane & 15, quad = lane >> 4;
    int ebase = blockIdx.x * 64 + w * 16;
    int e = ebase + l15;
    int src = ei[e], dst = ei[N_EDGES + e];

    // A-frags: a[0..1]=src halves, a[2..3]=dst halves, a[4]=[ea|1|0]
    short8 a[5];
#pragma unroll
    for (int kb = 0; kb < 2; kb++) {
        a[kb]     = *(const short8*)(hb + (size_t)src * 64 + kb * 32 + quad * 8);
        a[2 + kb] = *(const short8*)(hb + (size_t)dst * 64 + kb * 32 + quad * 8);
    }
    {
        union { short8 v; unsigned short u[8]; } tea;
#pragma unroll
        for (int j = 0; j < 8; j++) {
            float vv = 0.f;
            if (quad == 0) vv = (j < 5) ? ea[(size_t)e * 5 + j] : (j == 5 ? 1.f : 0.f);
            tea.u[j] = f2bf(vv);
        }
        a[4] = tea.v;
    }

    // layer 1: 20 MFMA
    float4v acc1[4] = {};
#pragma unroll
    for (int kb = 0; kb < 5; kb++)
#pragma unroll
        for (int nf = 0; nf < 4; nf++) {
            short8 b = *(const short8*)(wd1f + (size_t)((kb * 4 + nf) * 64 + lane) * 8);
            acc1[nf] = __builtin_amdgcn_mfma_f32_16x16x32_bf16(a[kb], b, acc1[nf], 0, 0, 0);
        }
    // d1 -> LDS in A-frag order: value at (row=quad*4+r, col=nf*16+l15)
    // frag kb'=nf>>1, lane'=((nf&1)*2+(l15>>3))*16 + quad*4+r, j'=l15&7
#pragma unroll
    for (int nf = 0; nf < 4; nf++) {
        int kbp = nf >> 1;
        int lanep_hi = ((nf & 1) * 2 + (l15 >> 3)) * 16;
        int jp = l15 & 7;
#pragma unroll
        for (int r = 0; r < 4; r++) {
            float v = acc1[nf][r];
            d1f[w][kbp * 512 + (lanep_hi + quad * 4 + r) * 8 + jp] = f2bf(v > 0.f ? v : 0.f);
        }
    }
    // layer 2: K=64, N=32 -> 4 MFMA  (intra-wave LDS dependency only)
    float4v acc2[2] = {};
#pragma unroll
    for (int kb = 0; kb < 2; kb++) {
        short8 a2 = *(const short8*)(&d1f[w][kb * 512 + lane * 8]);
#pragma unroll
        for (int nf = 0; nf < 2; nf++) {
            short8 b = *(const short8*)(wd2f + (size_t)((kb * 2 + nf) * 64 + lane) * 8);
            acc2[nf] = __builtin_amdgcn_mfma_f32_16x16x32_bf16(a2, b, acc2[nf], 0, 0, 0);
        }
    }
#pragma unroll
    for (int nf = 0; nf < 2; nf++) {
        int c = nf * 16 + l15;
        float bias = bd2[c];
#pragma unroll
        for (int r = 0; r < 4; r++) {
            float v = acc2[nf][r] + bias;
            d2s[w][(quad * 4 + r) * 33 + c] = v > 0.f ? v : 0.f;
        }
    }
    // layer 3: one (edge,t) per lane
    {
        int e_l = lane >> 2, t = lane & 3;
        float s = bd3[t];
        const float* w3 = Wd3 + t * 32;
        const float* dr = &d2s[w][e_l * 33];
#pragma unroll
        for (int k = 0; k < 32; k++) s += w3[k] * dr[k];
        out[(size_t)(ebase + e_l) * 4 + t] = s;
    }
}

extern "C" void kernel_launch(void* const* d_in, const int* in_sizes, int n_in,
                              void* d_out, int out_size, void* d_ws, size_t ws_size,
                              hipStream_t stream)
{
    const float* x      = (const float*)d_in[0];
    const int*   ei     = (const int*)d_in[1];
    const float* ea     = (const float*)d_in[2];
    const float* u      = (const float*)d_in[3];
    const float* Wp     = (const float*)d_in[4];
    const float* bp     = (const float*)d_in[5];
    const float* We1    = (const float*)d_in[6];
    const float* be1    = (const float*)d_in[7];
    const float* We2    = (const float*)d_in[8];
    const float* be2    = (const float*)d_in[9];
    const float* root   = (const float*)d_in[10];
    const float* conv_b = (const float*)d_in[11];
    const float* Wih    = (const float*)d_in[12];
    const float* bih    = (const float*)d_in[13];
    const float* Whh    = (const float*)d_in[14];
    const float* bhh    = (const float*)d_in[15];
    const float* Wd1    = (const float*)d_in[16];
    const float* bd1    = (const float*)d_in[17];
    const float* Wd2    = (const float*)d_in[18];
    const float* bd2    = (const float*)d_in[19];
    const float* Wd3    = (const float*)d_in[20];
    const float* bd3    = (const float*)d_in[21];
    float* out = (float*)d_out;

    char* ws = (char*)d_ws;
    size_t off = 0;
    auto take = [&](size_t bytes) -> char* {
        char* p = ws + off; off = (off + bytes + 255) & ~(size_t)255; return p;
    };
    float*          h      = (float*)take((size_t)N_NODES * 64 * 4);
    unsigned short* hb     = (unsigned short*)take((size_t)N_NODES * 64 * 2);
    unsigned short* hid    = (unsigned short*)take((size_t)N_EDGES * 64 * 2);
    float*          agg    = (float*)take((size_t)N_NODES * 64 * 4);
    float*          cnts   = (float*)take((size_t)N_NODES * 4);
    unsigned short* w2tf   = (unsigned short*)take((size_t)65 * 4096 * 2);
    unsigned short* rootTf = (unsigned short*)take((size_t)4096 * 2);
    unsigned short* wcombf = (unsigned short*)take((size_t)32768 * 2);
    unsigned short* wd1f   = (unsigned short*)take((size_t)10240 * 2);
    unsigned short* wd2f   = (unsigned short*)take((size_t)2048 * 2);
    (void)ws_size;

    hipMemsetAsync(cnts, 0, (size_t)N_NODES * 4, stream);
    hipMemsetAsync(agg, 0, (size_t)N_NODES * 64 * 4, stream);
    k_prep<<<144, 256, 0, stream>>>(root, Wih, Whh, rootTf, wcombf);
    k_prep_w2t<<<1040, 256, 0, stream>>>(We2, be2, w2tf);
    k_prep_dec<<<48, 256, 0, stream>>>(Wd1, bd1, Wd2, wd1f, wd2f);
    k_proj<<<8192, 256, 0, stream>>>(x, u, Wp, bp, h, hb);
    k_edge_hidden<<<8192, 256, 0, stream>>>(ea, We1, be1, hid);
    k_counts<<<128, 256, 0, stream>>>(ei, cnts);

    for (int s = 0; s < STEPS; s++) {
        k_msg_fused<<<N_EDGES / 32, 256, 0, stream>>>(hid, hb, w2tf, ei, agg);
        k_node<<<N_NODES / 64, 256, 0, stream>>>(hb, rootTf, wcombf, agg, cnts,
                                                 conv_b, bih, bhh, h, hb);
    }
    k_decoder<<<N_EDGES / 64, 256, 0, stream>>>(hb, ei, ea, wd1f, wd2f, bd2,
                                                Wd3, bd3, out);
}

// Round 6
// 297.002 us; speedup vs baseline: 3.0908x; 1.1244x over previous
//
#include <hip/hip_runtime.h>
#include <hip/hip_bf16.h>
#include <stdint.h>

// MPNN latency predictor, MI355X — round 6.
// vs R5: (1) k_msg_fused: 512-thread blocks (4 mf-waves x 2 kh-waves), 64
// edges/block -> each staged 16KB kk-block feeds 64 edges (L2 staging traffic
// halved to 266MB/dispatch; stage cadence ~550cyc < compute ~760cyc).
// (2) kh partial sums merged in LDS -> atomics halved (2.1M lane-atomics).
// (3) all setup (preps, proj, edge_hidden, agg/cnts zero) fused into ONE
// k_setup kernel; memsets removed; 14 -> 9 dispatches.

#define N_NODES 32768
#define N_EDGES 32768
#define STEPS 3

typedef __attribute__((ext_vector_type(8))) short short8;   // 8 bf16 = 4 VGPRs
typedef __attribute__((ext_vector_type(4))) float float4v;  // MFMA C/D

__device__ __forceinline__ float bf2f(unsigned short u) {
    union { unsigned int i; float f; } v; v.i = ((unsigned int)u) << 16; return v.f;
}
__device__ __forceinline__ unsigned short f2bf(float f) {  // RNE
    union { float f; unsigned int i; } v; v.f = f;
    unsigned int x = v.i;
    return (unsigned short)((x + 0x7fffu + ((x >> 16) & 1u)) >> 16);
}
__device__ __forceinline__ unsigned int fbits(float f) {
    union { float f; unsigned int i; } v; v.f = f; return v.i;
}

// pack 8 products hv*hf[j] into a bf16x8 A-frag: round-half-up + v_perm pack
__device__ __forceinline__ short8 packA(float hv, const float* hf) {
    union { short8 v; unsigned int u[4]; } r;
#pragma unroll
    for (int p = 0; p < 4; p++) {
        unsigned int p0 = fbits(hv * hf[2 * p]) + 0x8000u;
        unsigned int p1 = fbits(hv * hf[2 * p + 1]) + 0x8000u;
        r.u[p] = __builtin_amdgcn_perm(p1, p0, 0x07060302u);  // {hi16(p0), hi16(p1)}
    }
    return r.v;
}

// async global->LDS, 16B/lane; lds dest = wave-uniform base + lane*16
__device__ __forceinline__ void gload_lds16(const void* g, void* l) {
    __builtin_amdgcn_global_load_lds(
        (__attribute__((address_space(1))) void*)g,
        (__attribute__((address_space(3))) void*)l, 16, 0, 0);
}

// ===================== fused setup kernel ==================================
// blockIdx segments:
//  [0,144)      rootTf (4096) + wcombf (32768)      — frag-interleaved
//  [144,1184)   w2tf (266240)                        — frag-interleaved
//  [1184,1232)  wd1f (10240) + wd2f (2048)           — frag-interleaved
//  [1232,9424)  proj: h = tanh([x,u]@Wp^T+bp), + hb
//  [9424,17616) edge hidden: hid = relu(ea@We1^T+be1)
//  [17616,19696) zero aggcnt (2129920 floats, float4 stores)
__global__ __launch_bounds__(256) void k_setup(
    const float* __restrict__ root, const float* __restrict__ Wih,
    const float* __restrict__ Whh,
    const float* __restrict__ We2, const float* __restrict__ be2,
    const float* __restrict__ Wd1, const float* __restrict__ bd1,
    const float* __restrict__ Wd2,
    const float* __restrict__ x, const float* __restrict__ u,
    const float* __restrict__ Wp, const float* __restrict__ bp,
    const float* __restrict__ ea, const float* __restrict__ We1,
    const float* __restrict__ be1,
    unsigned short* __restrict__ rootTf, unsigned short* __restrict__ wcombf,
    unsigned short* __restrict__ w2tf,
    unsigned short* __restrict__ wd1f, unsigned short* __restrict__ wd2f,
    float* __restrict__ h, unsigned short* __restrict__ hb,
    unsigned short* __restrict__ hid, float* __restrict__ aggcnt)
{
    int b = blockIdx.x, tid = threadIdx.x;
    if (b < 144) {
        int i = b * 256 + tid;
        if (i < 4096) {
            int j = i & 7, lane = (i >> 3) & 63, g = i >> 9;   // g<8
            int kb = g >> 2, nf = g & 3;
            int o = nf * 16 + (lane & 15);
            int k = kb * 32 + (lane >> 4) * 8 + j;
            rootTf[i] = f2bf(root[k * 64 + o]);
        } else if (i < 4096 + 32768) {
            int t = i - 4096;
            int j = t & 7, lane = (t >> 3) & 63, g = t >> 9;   // g<64
            int kb = g >> 4, nf = g & 15;
            int cp = nf * 16 + (lane & 15);
            int k = kb * 32 + (lane >> 4) * 8 + j;
            float v;
            if (cp < 128)      v = (k < 64) ? Wih[cp * 64 + k] : Whh[cp * 64 + (k - 64)];
            else if (cp < 192) v = (k < 64) ? Wih[cp * 64 + k] : 0.f;
            else               v = (k < 64) ? 0.f : Whh[(cp - 64) * 64 + (k - 64)];
            wcombf[t] = f2bf(v);
        }
    } else if (b < 1184) {
        int t = (b - 144) * 256 + tid;   // t < 266240
        if (t < 65 * 4096) {
            int kk = t >> 12, r = t & 4095;
            int j = r & 7, lane = (r >> 3) & 63, g = r >> 9;  // g<8
            int half = g >> 2, nf = g & 3;
            int o = nf * 16 + (lane & 15);
            int hh = half * 32 + (lane >> 4) * 8 + j;
            float v = (kk < 64) ? We2[((size_t)(hh * 64 + o)) * 64 + kk]
                                : be2[(size_t)hh * 64 + o];
            w2tf[t] = f2bf(v);
        }
    } else if (b < 1232) {
        int i = (b - 1184) * 256 + tid;
        if (i < 10240) {
            int j = i & 7, lane = (i >> 3) & 63, g = i >> 9;  // g<20
            int kb = g >> 2, nf = g & 3;
            int o = nf * 16 + (lane & 15);
            int k = kb * 32 + (lane >> 4) * 8 + j;
            float v = (k < 133) ? Wd1[(size_t)o * 133 + k] : (k == 133 ? bd1[o] : 0.f);
            wd1f[i] = f2bf(v);
        } else if (i < 10240 + 2048) {
            int t = i - 10240;
            int j = t & 7, lane = (t >> 3) & 63, g = t >> 9;  // g<4
            int kb = g >> 1, nf = g & 1;
            int o = nf * 16 + (lane & 15);
            int k = kb * 32 + (lane >> 4) * 8 + j;
            wd2f[t] = f2bf(Wd2[(size_t)o * 64 + k]);
        }
    } else if (b < 9424) {
        int idx = (b - 1232) * 256 + tid;
        int n = idx >> 6, j = idx & 63;
        const float* wr = Wp + j * 23;
        const float* xr = x + (size_t)n * 12;
        float s = bp[j];
#pragma unroll
        for (int i = 0; i < 12; i++) s += xr[i] * wr[i];
#pragma unroll
        for (int i = 0; i < 11; i++) s += u[i] * wr[12 + i];
        float v = tanhf(s);
        h[idx] = v; hb[idx] = f2bf(v);
    } else if (b < 17616) {
        int idx = (b - 9424) * 256 + tid;
        int e = idx >> 6, j = idx & 63;
        float s = be1[j];
#pragma unroll
        for (int i = 0; i < 5; i++) s += ea[(size_t)e * 5 + i] * We1[j * 5 + i];
        hid[idx] = f2bf(s > 0.f ? s : 0.f);
    } else {
        int idx = (b - 17616) * 1024 + tid * 4;
        if (idx < 2129920) {
            float4v z = {0.f, 0.f, 0.f, 0.f};
            *(float4v*)(aggcnt + idx) = z;
        }
    }
}

__global__ __launch_bounds__(256) void k_counts(
    const int* __restrict__ ei, float* __restrict__ counts)
{
    int i = blockIdx.x * 256 + threadIdx.x;
    if (i < N_EDGES) atomicAdd(&counts[ei[N_EDGES + i]], 1.0f);
}

// ===================== fused msg GEMM ======================================
// 512 threads = 8 waves: wave = kh*4 + mf. 64 edges/block (mf picks 16-edge
// group), kh picks K-half (kh0: kk 0..31, kh1: kk 32..64 incl bias row).
// Per kh: double-buffered 8KB LDS staging shared by all 4 mf-waves (each
// staged block feeds 64 edges -> half the L2 traffic of R5). kh partial sums
// merged in LDS; only kh0 waves issue atomics (2.1M lane-atomics/step).
__global__ __launch_bounds__(512) void k_msg_fused(
    const unsigned short* __restrict__ hid,   // (E,64) bf16
    const unsigned short* __restrict__ hb,    // (N,64) bf16
    const unsigned short* __restrict__ w2tf,  // (65*4096) frag-interleaved
    const int* __restrict__ ei,
    float* __restrict__ agg)
{
    __shared__ unsigned short buf[2][2][4096];   // [kh][dbuf] 8KB each = 32KB
    int tid = threadIdx.x, wave = tid >> 6, lane = tid & 63;
    int l15 = lane & 15, quad = lane >> 4;
    int mf = wave & 3, kh = wave >> 2;
    int ebase = blockIdx.x * 64 + mf * 16;
    int e_a = ebase + l15;
    int src = ei[e_a];

    // this kh-half's 32 hid values for this lane's edge
    union { short8 v[4]; unsigned short u[32]; } hrow;
#pragma unroll
    for (int i = 0; i < 4; i++)
        hrow.v[i] = *(const short8*)(hid + (size_t)e_a * 64 + kh * 32 + i * 8);

    float hf0[8], hf1[8];
    {
        short8 h0 = *(const short8*)(hb + (size_t)src * 64 + quad * 8);
        short8 h1 = *(const short8*)(hb + (size_t)src * 64 + 32 + quad * 8);
#pragma unroll
        for (int j = 0; j < 8; j++) {
            hf0[j] = bf2f((unsigned short)h0[j]);
            hf1[j] = bf2f((unsigned short)h1[j]);
        }
    }

    // stage kk-block kkv into buf[kh][db]; wave mf stages chunks mf*2, mf*2+1
    auto stage = [&](int kkv, int db) {
        const unsigned short* g = w2tf + (size_t)kkv * 4096;
#pragma unroll
        for (int c = 0; c < 2; c++) {
            int chunk = mf * 2 + c;
            gload_lds16(g + (size_t)chunk * 512 + lane * 8, &buf[kh][db][chunk * 512]);
        }
    };

    int kk0 = kh ? 32 : 0;
    stage(kk0, 0);

    float4v acc[4] = {};
    int cur = 0;
#pragma unroll
    for (int i = 0; i <= 32; i++) {
        __syncthreads();   // staging of buf[*][cur] complete; prev reads done
        if ((kh == 0 && i + 1 < 32) || (kh == 1 && i + 1 <= 32))
            stage(kk0 + i + 1, cur ^ 1);
        bool active = (kh == 1) || (i < 32);
        if (active) {
            float hv = (kh && i == 32) ? 1.0f : bf2f(hrow.u[i & 31]);
            short8 a0 = packA(hv, hf0);
            short8 a1 = packA(hv, hf1);
            const unsigned short* bp = &buf[kh][cur][0];
#pragma unroll
            for (int nf = 0; nf < 4; nf++) {
                short8 b0 = *(const short8*)(bp + (0 * 4 + nf) * 512 + lane * 8);
                acc[nf] = __builtin_amdgcn_mfma_f32_16x16x32_bf16(a0, b0, acc[nf], 0, 0, 0);
            }
#pragma unroll
            for (int nf = 0; nf < 4; nf++) {
                short8 b1 = *(const short8*)(bp + (1 * 4 + nf) * 512 + lane * 8);
                acc[nf] = __builtin_amdgcn_mfma_f32_16x16x32_bf16(a1, b1, acc[nf], 0, 0, 0);
            }
        }
        cur ^= 1;
    }

    // merge kh partial sums through LDS (reuse staging buffer: 16KB needed)
    __syncthreads();
    float* mg = (float*)&buf[0][0][0];
    if (kh == 1) {
#pragma unroll
        for (int nf = 0; nf < 4; nf++)
#pragma unroll
            for (int r = 0; r < 4; r++)
                mg[mf * 1024 + lane * 16 + nf * 4 + r] = acc[nf][r];
    }
    __syncthreads();
    if (kh == 0) {
        int dsts[4];
#pragma unroll
        for (int r = 0; r < 4; r++) dsts[r] = ei[N_EDGES + ebase + quad * 4 + r];
#pragma unroll
        for (int nf = 0; nf < 4; nf++)
#pragma unroll
            for (int r = 0; r < 4; r++)
                atomicAdd(agg + (size_t)dsts[r] * 64 + nf * 16 + l15,
                          acc[nf][r] + mg[mf * 1024 + lane * 16 + nf * 4 + r]);
    }
}

// ===================== fused node update ===================================
__global__ __launch_bounds__(256) void k_node(
    const unsigned short* __restrict__ hb_in,
    const unsigned short* __restrict__ rootTf,
    const unsigned short* __restrict__ wcombf,
    float* __restrict__ agg, const float* __restrict__ counts,
    const float* __restrict__ conv_b,
    const float* __restrict__ bih, const float* __restrict__ bhh,
    float* __restrict__ h, unsigned short* __restrict__ hb_out)
{
    __shared__ unsigned short m_lds[64 * 72];
    int tid = threadIdx.x, w = tid >> 6, lane = tid & 63;
    int l15 = lane & 15, quad = lane >> 4;
    int node0 = blockIdx.x * 64;
    int row0 = w * 16;

    float4v acc1[4] = {};
    {
        short8 a1[2];
#pragma unroll
        for (int kb = 0; kb < 2; kb++)
            a1[kb] = *(const short8*)(hb_in + (size_t)(node0 + row0 + l15) * 64 + kb * 32 + quad * 8);
#pragma unroll
        for (int kb = 0; kb < 2; kb++)
#pragma unroll
            for (int nf = 0; nf < 4; nf++) {
                short8 b = *(const short8*)(rootTf + (size_t)((kb * 4 + nf) * 64 + lane) * 8);
                acc1[nf] = __builtin_amdgcn_mfma_f32_16x16x32_bf16(a1[kb], b, acc1[nf], 0, 0, 0);
            }
    }
#pragma unroll
    for (int rr = 0; rr < 4; rr++) {
        int nl = row0 + quad * 4 + rr;
        float cnt = counts[node0 + nl]; if (cnt < 1.f) cnt = 1.f;
        float rcp = 1.f / cnt;
#pragma unroll
        for (int nf = 0; nf < 4; nf++) {
            int c = nf * 16 + l15;
            float* ap = agg + (size_t)(node0 + nl) * 64 + c;
            float av = *ap;
            *ap = 0.f;
            float mv = av * rcp + acc1[nf][rr] + conv_b[c];
            m_lds[nl * 72 + c] = f2bf(mv > 0.f ? mv : 0.f);
        }
    }
    __syncthreads();

    float4v acc2[16] = {};
#pragma unroll
    for (int kb = 0; kb < 4; kb++) {
        short8 a2;
        if (kb < 2)
            a2 = *(const short8*)(m_lds + (row0 + l15) * 72 + kb * 32 + quad * 8);
        else
            a2 = *(const short8*)(hb_in + (size_t)(node0 + row0 + l15) * 64 + (kb - 2) * 32 + quad * 8);
#pragma unroll
        for (int nf = 0; nf < 16; nf++) {
            short8 b = *(const short8*)(wcombf + (size_t)((kb * 16 + nf) * 64 + lane) * 8);
            acc2[nf] = __builtin_amdgcn_mfma_f32_16x16x32_bf16(a2, b, acc2[nf], 0, 0, 0);
        }
    }

#pragma unroll
    for (int nf0 = 0; nf0 < 4; nf0++) {
        int c = nf0 * 16 + l15;
        float br = bih[c] + bhh[c];
        float bz = bih[64 + c] + bhh[64 + c];
        float bni = bih[128 + c], bnh = bhh[128 + c];
#pragma unroll
        for (int rr = 0; rr < 4; rr++) {
            int node = node0 + row0 + quad * 4 + rr;
            float gr = 1.f / (1.f + __expf(-(acc2[nf0][rr] + br)));
            float gz = 1.f / (1.f + __expf(-(acc2[nf0 + 4][rr] + bz)));
            float ng = tanhf(acc2[nf0 + 8][rr] + bni + gr * (acc2[nf0 + 12][rr] + bnh));
            float ho = h[(size_t)node * 64 + c];
            float hn = (1.f - gz) * ng + gz * ho;
            h[(size_t)node * 64 + c] = hn;
            hb_out[(size_t)node * 64 + c] = f2bf(hn);
        }
    }
}

// ===================== MFMA decoder ========================================
__global__ __launch_bounds__(256) void k_decoder(
    const unsigned short* __restrict__ hb, const int* __restrict__ ei,
    const float* __restrict__ ea,
    const unsigned short* __restrict__ wd1f, const unsigned short* __restrict__ wd2f,
    const float* __restrict__ bd2,
    const float* __restrict__ Wd3, const float* __restrict__ bd3,
    float* __restrict__ out)
{
    __shared__ unsigned short d1f[4][1024];  // per-wave: 2 frags x 512
    __shared__ float d2s[4][16 * 33];        // per-wave: 16 edges x 32 (+pad)
    int tid = threadIdx.x, w = tid >> 6, lane = tid & 63;
    int l15 = lane & 15, quad = lane >> 4;
    int ebase = blockIdx.x * 64 + w * 16;
    int e = ebase + l15;
    int src = ei[e], dst = ei[N_EDGES + e];

    short8 a[5];
#pragma unroll
    for (int kb = 0; kb < 2; kb++) {
        a[kb]     = *(const short8*)(hb + (size_t)src * 64 + kb * 32 + quad * 8);
        a[2 + kb] = *(const short8*)(hb + (size_t)dst * 64 + kb * 32 + quad * 8);
    }
    {
        union { short8 v; unsigned short u[8]; } tea;
#pragma unroll
        for (int j = 0; j < 8; j++) {
            float vv = 0.f;
            if (quad == 0) vv = (j < 5) ? ea[(size_t)e * 5 + j] : (j == 5 ? 1.f : 0.f);
            tea.u[j] = f2bf(vv);
        }
        a[4] = tea.v;
    }

    float4v acc1[4] = {};
#pragma unroll
    for (int kb = 0; kb < 5; kb++)
#pragma unroll
        for (int nf = 0; nf < 4; nf++) {
            short8 b = *(const short8*)(wd1f + (size_t)((kb * 4 + nf) * 64 + lane) * 8);
            acc1[nf] = __builtin_amdgcn_mfma_f32_16x16x32_bf16(a[kb], b, acc1[nf], 0, 0, 0);
        }
#pragma unroll
    for (int nf = 0; nf < 4; nf++) {
        int kbp = nf >> 1;
        int lanep_hi = ((nf & 1) * 2 + (l15 >> 3)) * 16;
        int jp = l15 & 7;
#pragma unroll
        for (int r = 0; r < 4; r++) {
            float v = acc1[nf][r];
            d1f[w][kbp * 512 + (lanep_hi + quad * 4 + r) * 8 + jp] = f2bf(v > 0.f ? v : 0.f);
        }
    }
    float4v acc2[2] = {};
#pragma unroll
    for (int kb = 0; kb < 2; kb++) {
        short8 a2 = *(const short8*)(&d1f[w][kb * 512 + lane * 8]);
#pragma unroll
        for (int nf = 0; nf < 2; nf++) {
            short8 b = *(const short8*)(wd2f + (size_t)((kb * 2 + nf) * 64 + lane) * 8);
            acc2[nf] = __builtin_amdgcn_mfma_f32_16x16x32_bf16(a2, b, acc2[nf], 0, 0, 0);
        }
    }
#pragma unroll
    for (int nf = 0; nf < 2; nf++) {
        int c = nf * 16 + l15;
        float bias = bd2[c];
#pragma unroll
        for (int r = 0; r < 4; r++) {
            float v = acc2[nf][r] + bias;
            d2s[w][(quad * 4 + r) * 33 + c] = v > 0.f ? v : 0.f;
        }
    }
    {
        int e_l = lane >> 2, t = lane & 3;
        float s = bd3[t];
        const float* w3 = Wd3 + t * 32;
        const float* dr = &d2s[w][e_l * 33];
#pragma unroll
        for (int k = 0; k < 32; k++) s += w3[k] * dr[k];
        out[(size_t)(ebase + e_l) * 4 + t] = s;
    }
}

extern "C" void kernel_launch(void* const* d_in, const int* in_sizes, int n_in,
                              void* d_out, int out_size, void* d_ws, size_t ws_size,
                              hipStream_t stream)
{
    const float* x      = (const float*)d_in[0];
    const int*   ei     = (const int*)d_in[1];
    const float* ea     = (const float*)d_in[2];
    const float* u      = (const float*)d_in[3];
    const float* Wp     = (const float*)d_in[4];
    const float* bp     = (const float*)d_in[5];
    const float* We1    = (const float*)d_in[6];
    const float* be1    = (const float*)d_in[7];
    const float* We2    = (const float*)d_in[8];
    const float* be2    = (const float*)d_in[9];
    const float* root   = (const float*)d_in[10];
    const float* conv_b = (const float*)d_in[11];
    const float* Wih    = (const float*)d_in[12];
    const float* bih    = (const float*)d_in[13];
    const float* Whh    = (const float*)d_in[14];
    const float* bhh    = (const float*)d_in[15];
    const float* Wd1    = (const float*)d_in[16];
    const float* bd1    = (const float*)d_in[17];
    const float* Wd2    = (const float*)d_in[18];
    const float* bd2    = (const float*)d_in[19];
    const float* Wd3    = (const float*)d_in[20];
    const float* bd3    = (const float*)d_in[21];
    float* out = (float*)d_out;

    char* ws = (char*)d_ws;
    size_t off = 0;
    auto take = [&](size_t bytes) -> char* {
        char* p = ws + off; off = (off + bytes + 255) & ~(size_t)255; return p;
    };
    float*          h      = (float*)take((size_t)N_NODES * 64 * 4);
    unsigned short* hb     = (unsigned short*)take((size_t)N_NODES * 64 * 2);
    unsigned short* hid    = (unsigned short*)take((size_t)N_EDGES * 64 * 2);
    // agg (2097152 f) and cnts (32768 f) contiguous: zeroed together in setup
    float*          aggcnt = (float*)take((size_t)(N_NODES * 64 + N_NODES) * 4);
    float*          agg    = aggcnt;
    float*          cnts   = aggcnt + (size_t)N_NODES * 64;
    unsigned short* w2tf   = (unsigned short*)take((size_t)65 * 4096 * 2);
    unsigned short* rootTf = (unsigned short*)take((size_t)4096 * 2);
    unsigned short* wcombf = (unsigned short*)take((size_t)32768 * 2);
    unsigned short* wd1f   = (unsigned short*)take((size_t)10240 * 2);
    unsigned short* wd2f   = (unsigned short*)take((size_t)2048 * 2);
    (void)ws_size;

    k_setup<<<19696, 256, 0, stream>>>(root, Wih, Whh, We2, be2, Wd1, bd1, Wd2,
                                       x, u, Wp, bp, ea, We1, be1,
                                       rootTf, wcombf, w2tf, wd1f, wd2f,
                                       h, hb, hid, aggcnt);
    k_counts<<<128, 256, 0, stream>>>(ei, cnts);

    for (int s = 0; s < STEPS; s++) {
        k_msg_fused<<<N_EDGES / 64, 512, 0, stream>>>(hid, hb, w2tf, ei, agg);
        k_node<<<N_NODES / 64, 256, 0, stream>>>(hb, rootTf, wcombf, agg, cnts,
                                                 conv_b, bih, bhh, h, hb);
    }
    k_decoder<<<N_EDGES / 64, 256, 0, stream>>>(hb, ei, ea, wd1f, wd2f, bd2,
                                                Wd3, bd3, out);
}

// Round 7
// 267.016 us; speedup vs baseline: 3.4379x; 1.1123x over previous
//
#include <hip/hip_runtime.h>
#include <hip/hip_bf16.h>
#include <stdint.h>

// MPNN latency predictor, MI355X — round 7.
// vs R6: (1) k_msg_fused stages TWO kk-blocks per barrier (contiguous 16KB per
// kh, double-buffered, 64KB LDS, 2 blocks/CU) -> 17 barriers instead of 33;
// the ~600cyc vmcnt drain is now covered by doubled per-iter compute.
// (2) fp32 h array eliminated: GRU h_old read from hb (bf16) — its only
// consumer; saves 16MB/step HBM. (3) w2tf padded one block for tail prefetch.

#define N_NODES 32768
#define N_EDGES 32768
#define STEPS 3

typedef __attribute__((ext_vector_type(8))) short short8;   // 8 bf16 = 4 VGPRs
typedef __attribute__((ext_vector_type(4))) float float4v;  // MFMA C/D

__device__ __forceinline__ float bf2f(unsigned short u) {
    union { unsigned int i; float f; } v; v.i = ((unsigned int)u) << 16; return v.f;
}
__device__ __forceinline__ unsigned short f2bf(float f) {  // RNE
    union { float f; unsigned int i; } v; v.f = f;
    unsigned int x = v.i;
    return (unsigned short)((x + 0x7fffu + ((x >> 16) & 1u)) >> 16);
}
__device__ __forceinline__ unsigned int fbits(float f) {
    union { float f; unsigned int i; } v; v.f = f; return v.i;
}

// pack 8 products hv*hf[j] into a bf16x8 A-frag: round-half-up + v_perm pack
__device__ __forceinline__ short8 packA(float hv, const float* hf) {
    union { short8 v; unsigned int u[4]; } r;
#pragma unroll
    for (int p = 0; p < 4; p++) {
        unsigned int p0 = fbits(hv * hf[2 * p]) + 0x8000u;
        unsigned int p1 = fbits(hv * hf[2 * p + 1]) + 0x8000u;
        r.u[p] = __builtin_amdgcn_perm(p1, p0, 0x07060302u);  // {hi16(p0), hi16(p1)}
    }
    return r.v;
}

// async global->LDS, 16B/lane; lds dest = wave-uniform base + lane*16
__device__ __forceinline__ void gload_lds16(const void* g, void* l) {
    __builtin_amdgcn_global_load_lds(
        (__attribute__((address_space(1))) void*)g,
        (__attribute__((address_space(3))) void*)l, 16, 0, 0);
}

// ===================== fused setup kernel ==================================
// blockIdx segments:
//  [0,144)       rootTf (4096) + wcombf (32768)      — frag-interleaved
//  [144,1184)    w2tf (266240 valid + 4096 pad)       — frag-interleaved
//  [1184,1232)   wd1f (10240) + wd2f (2048)           — frag-interleaved
//  [1232,9424)   proj: hb = bf16(tanh([x,u]@Wp^T+bp))
//  [9424,17616)  edge hidden: hid = relu(ea@We1^T+be1)
//  [17616,19696) zero aggcnt (2129920 floats, float4 stores)
__global__ __launch_bounds__(256) void k_setup(
    const float* __restrict__ root, const float* __restrict__ Wih,
    const float* __restrict__ Whh,
    const float* __restrict__ We2, const float* __restrict__ be2,
    const float* __restrict__ Wd1, const float* __restrict__ bd1,
    const float* __restrict__ Wd2,
    const float* __restrict__ x, const float* __restrict__ u,
    const float* __restrict__ Wp, const float* __restrict__ bp,
    const float* __restrict__ ea, const float* __restrict__ We1,
    const float* __restrict__ be1,
    unsigned short* __restrict__ rootTf, unsigned short* __restrict__ wcombf,
    unsigned short* __restrict__ w2tf,
    unsigned short* __restrict__ wd1f, unsigned short* __restrict__ wd2f,
    unsigned short* __restrict__ hb,
    unsigned short* __restrict__ hid, float* __restrict__ aggcnt)
{
    int b = blockIdx.x, tid = threadIdx.x;
    if (b < 144) {
        int i = b * 256 + tid;
        if (i < 4096) {
            int j = i & 7, lane = (i >> 3) & 63, g = i >> 9;   // g<8
            int kb = g >> 2, nf = g & 3;
            int o = nf * 16 + (lane & 15);
            int k = kb * 32 + (lane >> 4) * 8 + j;
            rootTf[i] = f2bf(root[k * 64 + o]);
        } else if (i < 4096 + 32768) {
            int t = i - 4096;
            int j = t & 7, lane = (t >> 3) & 63, g = t >> 9;   // g<64
            int kb = g >> 4, nf = g & 15;
            int cp = nf * 16 + (lane & 15);
            int k = kb * 32 + (lane >> 4) * 8 + j;
            float v;
            if (cp < 128)      v = (k < 64) ? Wih[cp * 64 + k] : Whh[cp * 64 + (k - 64)];
            else if (cp < 192) v = (k < 64) ? Wih[cp * 64 + k] : 0.f;
            else               v = (k < 64) ? 0.f : Whh[(cp - 64) * 64 + (k - 64)];
            wcombf[t] = f2bf(v);
        }
    } else if (b < 1184) {
        int t = (b - 144) * 256 + tid;   // t < 266240
        if (t < 65 * 4096) {
            int kk = t >> 12, r = t & 4095;
            int j = r & 7, lane = (r >> 3) & 63, g = r >> 9;  // g<8
            int half = g >> 2, nf = g & 3;
            int o = nf * 16 + (lane & 15);
            int hh = half * 32 + (lane >> 4) * 8 + j;
            float v = (kk < 64) ? We2[((size_t)(hh * 64 + o)) * 64 + kk]
                                : be2[(size_t)hh * 64 + o];
            w2tf[t] = f2bf(v);
        }
    } else if (b < 1232) {
        int i = (b - 1184) * 256 + tid;
        if (i < 10240) {
            int j = i & 7, lane = (i >> 3) & 63, g = i >> 9;  // g<20
            int kb = g >> 2, nf = g & 3;
            int o = nf * 16 + (lane & 15);
            int k = kb * 32 + (lane >> 4) * 8 + j;
            float v = (k < 133) ? Wd1[(size_t)o * 133 + k] : (k == 133 ? bd1[o] : 0.f);
            wd1f[i] = f2bf(v);
        } else if (i < 10240 + 2048) {
            int t = i - 10240;
            int j = t & 7, lane = (t >> 3) & 63, g = t >> 9;  // g<4
            int kb = g >> 1, nf = g & 1;
            int o = nf * 16 + (lane & 15);
            int k = kb * 32 + (lane >> 4) * 8 + j;
            wd2f[t] = f2bf(Wd2[(size_t)o * 64 + k]);
        }
    } else if (b < 9424) {
        int idx = (b - 1232) * 256 + tid;
        int n = idx >> 6, j = idx & 63;
        const float* wr = Wp + j * 23;
        const float* xr = x + (size_t)n * 12;
        float s = bp[j];
#pragma unroll
        for (int i = 0; i < 12; i++) s += xr[i] * wr[i];
#pragma unroll
        for (int i = 0; i < 11; i++) s += u[i] * wr[12 + i];
        hb[idx] = f2bf(tanhf(s));
    } else if (b < 17616) {
        int idx = (b - 9424) * 256 + tid;
        int e = idx >> 6, j = idx & 63;
        float s = be1[j];
#pragma unroll
        for (int i = 0; i < 5; i++) s += ea[(size_t)e * 5 + i] * We1[j * 5 + i];
        hid[idx] = f2bf(s > 0.f ? s : 0.f);
    } else {
        int idx = (b - 17616) * 1024 + tid * 4;
        if (idx < 2129920) {
            float4v z = {0.f, 0.f, 0.f, 0.f};
            *(float4v*)(aggcnt + idx) = z;
        }
    }
}

__global__ __launch_bounds__(256) void k_counts(
    const int* __restrict__ ei, float* __restrict__ counts)
{
    int i = blockIdx.x * 256 + threadIdx.x;
    if (i < N_EDGES) atomicAdd(&counts[ei[N_EDGES + i]], 1.0f);
}

// ===================== fused msg GEMM ======================================
// 512 threads = 8 waves: wave = kh*4 + mf. 64 edges/block, kh picks K-half
// (kh0: kk 0..31, kh1: kk 32..64 incl bias row). TWO kk per barrier: each kh
// stages a contiguous 16KB kk-pair (double-buffered; 64KB LDS total) shared
// by its 4 mf-waves. 17 barriers. kh partials merged in LDS; kh0 atomics.
__global__ __launch_bounds__(512, 4) void k_msg_fused(
    const unsigned short* __restrict__ hid,   // (E,64) bf16
    const unsigned short* __restrict__ hb,    // (N,64) bf16
    const unsigned short* __restrict__ w2tf,  // (66*4096) frag-interleaved
    const int* __restrict__ ei,
    float* __restrict__ agg)
{
    __shared__ unsigned short buf[2][2][8192];   // [kh][dbuf][2 kk x 4096] 64KB
    int tid = threadIdx.x, wave = tid >> 6, lane = tid & 63;
    int l15 = lane & 15, quad = lane >> 4;
    int mf = wave & 3, kh = wave >> 2;
    int ebase = blockIdx.x * 64 + mf * 16;
    int e_a = ebase + l15;
    int src = ei[e_a];

    // this kh-half's 32 hid values for this lane's edge
    union { short8 v[4]; unsigned short u[32]; } hrow;
#pragma unroll
    for (int i = 0; i < 4; i++)
        hrow.v[i] = *(const short8*)(hid + (size_t)e_a * 64 + kh * 32 + i * 8);

    float hf0[8], hf1[8];
    {
        short8 h0 = *(const short8*)(hb + (size_t)src * 64 + quad * 8);
        short8 h1 = *(const short8*)(hb + (size_t)src * 64 + 32 + quad * 8);
#pragma unroll
        for (int j = 0; j < 8; j++) {
            hf0[j] = bf2f((unsigned short)h0[j]);
            hf1[j] = bf2f((unsigned short)h1[j]);
        }
    }

    int kk0 = kh ? 32 : 0;
    // stage kk-pair `pair` (16KB contiguous: kks kk0+2p, kk0+2p+1) into
    // buf[kh][db]; wave mf stages chunks mf*4 .. mf*4+3 (1KB each)
    auto stage = [&](int pair, int db) {
        const unsigned short* g = w2tf + (size_t)(kk0 + 2 * pair) * 4096;
#pragma unroll
        for (int c = 0; c < 4; c++) {
            int chunk = mf * 4 + c;
            gload_lds16(g + (size_t)chunk * 512 + lane * 8, &buf[kh][db][chunk * 512]);
        }
    };

    stage(0, 0);

    float4v acc[4] = {};
    int cur = 0;
#pragma unroll
    for (int i = 0; i <= 16; i++) {
        __syncthreads();   // staging of buf[*][cur] complete; prev reads done
        if ((kh == 0 && i + 1 < 16) || (kh == 1 && i + 1 <= 16))
            stage(i + 1, cur ^ 1);
        int nkk = (kh == 0) ? (i < 16 ? 2 : 0) : (i < 16 ? 2 : 1);  // wave-uniform
        for (int s = 0; s < nkk; s++) {
            float hv = (kh == 1 && i == 16) ? 1.0f : bf2f(hrow.u[2 * i + s]);
            short8 a0 = packA(hv, hf0);
            short8 a1 = packA(hv, hf1);
            const unsigned short* bp = &buf[kh][cur][s * 4096];
#pragma unroll
            for (int nf = 0; nf < 4; nf++) {
                short8 b0 = *(const short8*)(bp + (0 * 4 + nf) * 512 + lane * 8);
                acc[nf] = __builtin_amdgcn_mfma_f32_16x16x32_bf16(a0, b0, acc[nf], 0, 0, 0);
            }
#pragma unroll
            for (int nf = 0; nf < 4; nf++) {
                short8 b1 = *(const short8*)(bp + (1 * 4 + nf) * 512 + lane * 8);
                acc[nf] = __builtin_amdgcn_mfma_f32_16x16x32_bf16(a1, b1, acc[nf], 0, 0, 0);
            }
        }
        cur ^= 1;
    }

    // merge kh partial sums through LDS (reuse staging buffer: 16KB needed)
    __syncthreads();
    float* mg = (float*)&buf[0][0][0];
    if (kh == 1) {
#pragma unroll
        for (int nf = 0; nf < 4; nf++)
#pragma unroll
            for (int r = 0; r < 4; r++)
                mg[mf * 1024 + lane * 16 + nf * 4 + r] = acc[nf][r];
    }
    __syncthreads();
    if (kh == 0) {
        int dsts[4];
#pragma unroll
        for (int r = 0; r < 4; r++) dsts[r] = ei[N_EDGES + ebase + quad * 4 + r];
#pragma unroll
        for (int nf = 0; nf < 4; nf++)
#pragma unroll
            for (int r = 0; r < 4; r++)
                atomicAdd(agg + (size_t)dsts[r] * 64 + nf * 16 + l15,
                          acc[nf][r] + mg[mf * 1024 + lane * 16 + nf * 4 + r]);
    }
}

// ===================== fused node update ===================================
// h_old comes from hb (bf16) — fp32 h array eliminated.
__global__ __launch_bounds__(256) void k_node(
    const unsigned short* __restrict__ hb_in,
    const unsigned short* __restrict__ rootTf,
    const unsigned short* __restrict__ wcombf,
    float* __restrict__ agg, const float* __restrict__ counts,
    const float* __restrict__ conv_b,
    const float* __restrict__ bih, const float* __restrict__ bhh,
    unsigned short* __restrict__ hb_out)
{
    __shared__ unsigned short m_lds[64 * 72];
    int tid = threadIdx.x, w = tid >> 6, lane = tid & 63;
    int l15 = lane & 15, quad = lane >> 4;
    int node0 = blockIdx.x * 64;
    int row0 = w * 16;

    float4v acc1[4] = {};
    {
        short8 a1[2];
#pragma unroll
        for (int kb = 0; kb < 2; kb++)
            a1[kb] = *(const short8*)(hb_in + (size_t)(node0 + row0 + l15) * 64 + kb * 32 + quad * 8);
#pragma unroll
        for (int kb = 0; kb < 2; kb++)
#pragma unroll
            for (int nf = 0; nf < 4; nf++) {
                short8 b = *(const short8*)(rootTf + (size_t)((kb * 4 + nf) * 64 + lane) * 8);
                acc1[nf] = __builtin_amdgcn_mfma_f32_16x16x32_bf16(a1[kb], b, acc1[nf], 0, 0, 0);
            }
    }
#pragma unroll
    for (int rr = 0; rr < 4; rr++) {
        int nl = row0 + quad * 4 + rr;
        float cnt = counts[node0 + nl]; if (cnt < 1.f) cnt = 1.f;
        float rcp = 1.f / cnt;
#pragma unroll
        for (int nf = 0; nf < 4; nf++) {
            int c = nf * 16 + l15;
            float* ap = agg + (size_t)(node0 + nl) * 64 + c;
            float av = *ap;
            *ap = 0.f;
            float mv = av * rcp + acc1[nf][rr] + conv_b[c];
            m_lds[nl * 72 + c] = f2bf(mv > 0.f ? mv : 0.f);
        }
    }
    __syncthreads();

    float4v acc2[16] = {};
#pragma unroll
    for (int kb = 0; kb < 4; kb++) {
        short8 a2;
        if (kb < 2)
            a2 = *(const short8*)(m_lds + (row0 + l15) * 72 + kb * 32 + quad * 8);
        else
            a2 = *(const short8*)(hb_in + (size_t)(node0 + row0 + l15) * 64 + (kb - 2) * 32 + quad * 8);
#pragma unroll
        for (int nf = 0; nf < 16; nf++) {
            short8 b = *(const short8*)(wcombf + (size_t)((kb * 16 + nf) * 64 + lane) * 8);
            acc2[nf] = __builtin_amdgcn_mfma_f32_16x16x32_bf16(a2, b, acc2[nf], 0, 0, 0);
        }
    }

#pragma unroll
    for (int nf0 = 0; nf0 < 4; nf0++) {
        int c = nf0 * 16 + l15;
        float br = bih[c] + bhh[c];
        float bz = bih[64 + c] + bhh[64 + c];
        float bni = bih[128 + c], bnh = bhh[128 + c];
#pragma unroll
        for (int rr = 0; rr < 4; rr++) {
            int node = node0 + row0 + quad * 4 + rr;
            float gr = 1.f / (1.f + __expf(-(acc2[nf0][rr] + br)));
            float gz = 1.f / (1.f + __expf(-(acc2[nf0 + 4][rr] + bz)));
            float ng = tanhf(acc2[nf0 + 8][rr] + bni + gr * (acc2[nf0 + 12][rr] + bnh));
            float ho = bf2f(hb_in[(size_t)node * 64 + c]);
            float hn = (1.f - gz) * ng + gz * ho;
            hb_out[(size_t)node * 64 + c] = f2bf(hn);
        }
    }
}

// ===================== MFMA decoder ========================================
__global__ __launch_bounds__(256) void k_decoder(
    const unsigned short* __restrict__ hb, const int* __restrict__ ei,
    const float* __restrict__ ea,
    const unsigned short* __restrict__ wd1f, const unsigned short* __restrict__ wd2f,
    const float* __restrict__ bd2,
    const float* __restrict__ Wd3, const float* __restrict__ bd3,
    float* __restrict__ out)
{
    __shared__ unsigned short d1f[4][1024];  // per-wave: 2 frags x 512
    __shared__ float d2s[4][16 * 33];        // per-wave: 16 edges x 32 (+pad)
    int tid = threadIdx.x, w = tid >> 6, lane = tid & 63;
    int l15 = lane & 15, quad = lane >> 4;
    int ebase = blockIdx.x * 64 + w * 16;
    int e = ebase + l15;
    int src = ei[e], dst = ei[N_EDGES + e];

    short8 a[5];
#pragma unroll
    for (int kb = 0; kb < 2; kb++) {
        a[kb]     = *(const short8*)(hb + (size_t)src * 64 + kb * 32 + quad * 8);
        a[2 + kb] = *(const short8*)(hb + (size_t)dst * 64 + kb * 32 + quad * 8);
    }
    {
        union { short8 v; unsigned short u[8]; } tea;
#pragma unroll
        for (int j = 0; j < 8; j++) {
            float vv = 0.f;
            if (quad == 0) vv = (j < 5) ? ea[(size_t)e * 5 + j] : (j == 5 ? 1.f : 0.f);
            tea.u[j] = f2bf(vv);
        }
        a[4] = tea.v;
    }

    float4v acc1[4] = {};
#pragma unroll
    for (int kb = 0; kb < 5; kb++)
#pragma unroll
        for (int nf = 0; nf < 4; nf++) {
            short8 b = *(const short8*)(wd1f + (size_t)((kb * 4 + nf) * 64 + lane) * 8);
            acc1[nf] = __builtin_amdgcn_mfma_f32_16x16x32_bf16(a[kb], b, acc1[nf], 0, 0, 0);
        }
#pragma unroll
    for (int nf = 0; nf < 4; nf++) {
        int kbp = nf >> 1;
        int lanep_hi = ((nf & 1) * 2 + (l15 >> 3)) * 16;
        int jp = l15 & 7;
#pragma unroll
        for (int r = 0; r < 4; r++) {
            float v = acc1[nf][r];
            d1f[w][kbp * 512 + (lanep_hi + quad * 4 + r) * 8 + jp] = f2bf(v > 0.f ? v : 0.f);
        }
    }
    float4v acc2[2] = {};
#pragma unroll
    for (int kb = 0; kb < 2; kb++) {
        short8 a2 = *(const short8*)(&d1f[w][kb * 512 + lane * 8]);
#pragma unroll
        for (int nf = 0; nf < 2; nf++) {
            short8 b = *(const short8*)(wd2f + (size_t)((kb * 2 + nf) * 64 + lane) * 8);
            acc2[nf] = __builtin_amdgcn_mfma_f32_16x16x32_bf16(a2, b, acc2[nf], 0, 0, 0);
        }
    }
#pragma unroll
    for (int nf = 0; nf < 2; nf++) {
        int c = nf * 16 + l15;
        float bias = bd2[c];
#pragma unroll
        for (int r = 0; r < 4; r++) {
            float v = acc2[nf][r] + bias;
            d2s[w][(quad * 4 + r) * 33 + c] = v > 0.f ? v : 0.f;
        }
    }
    {
        int e_l = lane >> 2, t = lane & 3;
        float s = bd3[t];
        const float* w3 = Wd3 + t * 32;
        const float* dr = &d2s[w][e_l * 33];
#pragma unroll
        for (int k = 0; k < 32; k++) s += w3[k] * dr[k];
        out[(size_t)(ebase + e_l) * 4 + t] = s;
    }
}

extern "C" void kernel_launch(void* const* d_in, const int* in_sizes, int n_in,
                              void* d_out, int out_size, void* d_ws, size_t ws_size,
                              hipStream_t stream)
{
    const float* x      = (const float*)d_in[0];
    const int*   ei     = (const int*)d_in[1];
    const float* ea     = (const float*)d_in[2];
    const float* u      = (const float*)d_in[3];
    const float* Wp     = (const float*)d_in[4];
    const float* bp     = (const float*)d_in[5];
    const float* We1    = (const float*)d_in[6];
    const float* be1    = (const float*)d_in[7];
    const float* We2    = (const float*)d_in[8];
    const float* be2    = (const float*)d_in[9];
    const float* root   = (const float*)d_in[10];
    const float* conv_b = (const float*)d_in[11];
    const float* Wih    = (const float*)d_in[12];
    const float* bih    = (const float*)d_in[13];
    const float* Whh    = (const float*)d_in[14];
    const float* bhh    = (const float*)d_in[15];
    const float* Wd1    = (const float*)d_in[16];
    const float* bd1    = (const float*)d_in[17];
    const float* Wd2    = (const float*)d_in[18];
    const float* bd2    = (const float*)d_in[19];
    const float* Wd3    = (const float*)d_in[20];
    const float* bd3    = (const float*)d_in[21];
    float* out = (float*)d_out;

    char* ws = (char*)d_ws;
    size_t off = 0;
    auto take = [&](size_t bytes) -> char* {
        char* p = ws + off; off = (off + bytes + 255) & ~(size_t)255; return p;
    };
    unsigned short* hb     = (unsigned short*)take((size_t)N_NODES * 64 * 2);
    unsigned short* hid    = (unsigned short*)take((size_t)N_EDGES * 64 * 2);
    // agg (2097152 f) and cnts (32768 f) contiguous: zeroed together in setup
    float*          aggcnt = (float*)take((size_t)(N_NODES * 64 + N_NODES) * 4);
    float*          agg    = aggcnt;
    float*          cnts   = aggcnt + (size_t)N_NODES * 64;
    unsigned short* w2tf   = (unsigned short*)take((size_t)66 * 4096 * 2);  // +1 pad blk
    unsigned short* rootTf = (unsigned short*)take((size_t)4096 * 2);
    unsigned short* wcombf = (unsigned short*)take((size_t)32768 * 2);
    unsigned short* wd1f   = (unsigned short*)take((size_t)10240 * 2);
    unsigned short* wd2f   = (unsigned short*)take((size_t)2048 * 2);
    (void)ws_size;

    k_setup<<<19696, 256, 0, stream>>>(root, Wih, Whh, We2, be2, Wd1, bd1, Wd2,
                                       x, u, Wp, bp, ea, We1, be1,
                                       rootTf, wcombf, w2tf, wd1f, wd2f,
                                       hb, hid, aggcnt);
    k_counts<<<128, 256, 0, stream>>>(ei, cnts);

    for (int s = 0; s < STEPS; s++) {
        k_msg_fused<<<N_EDGES / 64, 512, 0, stream>>>(hid, hb, w2tf, ei, agg);
        k_node<<<N_NODES / 64, 256, 0, stream>>>(hb, rootTf, wcombf, agg, cnts,
                                                 conv_b, bih, bhh, hb);
    }
    k_decoder<<<N_EDGES / 64, 256, 0, stream>>>(hb, ei, ea, wd1f, wd2f, bd2,
                                                Wd3, bd3, out);
}